// Round 1
// baseline (1414.172 us; speedup 1.0000x reference)
//
#include <hip/hip_runtime.h>
#include <math.h>

#define N_USER 24000
#define N_ITEM 8000
#define N_NODE 32000
#define N_EDGE 800000
#define NCH    32          // j-chunks for sim/topk
#define CHUNK  250         // N_ITEM / NCH
#define TJ     128         // j-tile staged in LDS
#define NEG_INF -1e30f

__device__ __forceinline__ float wred_sum(float v) {
#pragma unroll
  for (int off = 32; off; off >>= 1) v += __shfl_xor(v, off, 64);
  return v;
}

// ---------------- projection GEMM: out[M x 64] = X[M x K] @ W[K x 64] + b ----
__global__ __launch_bounds__(256) void gemm_bias64(
    const float* __restrict__ X, const float* __restrict__ W,
    const float* __restrict__ bias, float* __restrict__ out, int K)
{
  __shared__ float As[32 * 64];   // As[k][r]
  __shared__ float Bs[32 * 64];   // Bs[k][n]
  const int tid = threadIdx.x;
  const int m0 = blockIdx.x * 64;
  const int tr = tid >> 4, tc = tid & 15;
  float acc[4][4] = {};
  for (int k0 = 0; k0 < K; k0 += 32) {
    __syncthreads();
#pragma unroll
    for (int l = 0; l < 2; ++l) {
      int f4 = tid + l * 256;
      int r = f4 >> 3, kq = f4 & 7;        // A: 64 rows x 8 float4
      float4 a = *(const float4*)(X + (size_t)(m0 + r) * K + k0 + kq * 4);
      As[(kq * 4 + 0) * 64 + r] = a.x;
      As[(kq * 4 + 1) * 64 + r] = a.y;
      As[(kq * 4 + 2) * 64 + r] = a.z;
      As[(kq * 4 + 3) * 64 + r] = a.w;
      int kb = f4 >> 4, nq = f4 & 15;      // B: 32 rows x 16 float4
      *(float4*)(Bs + kb * 64 + nq * 4) =
          *(const float4*)(W + (size_t)(k0 + kb) * 64 + nq * 4);
    }
    __syncthreads();
#pragma unroll
    for (int k = 0; k < 32; ++k) {
      float4 a4 = *(const float4*)(As + k * 64 + tr * 4);
      float4 b4 = *(const float4*)(Bs + k * 64 + tc * 4);
      float av[4] = {a4.x, a4.y, a4.z, a4.w};
      float bv[4] = {b4.x, b4.y, b4.z, b4.w};
#pragma unroll
      for (int ri = 0; ri < 4; ++ri)
#pragma unroll
        for (int ci = 0; ci < 4; ++ci) acc[ri][ci] += av[ri] * bv[ci];
    }
  }
  float4 bb = *(const float4*)(bias + tc * 4);
  float bv[4] = {bb.x, bb.y, bb.z, bb.w};
#pragma unroll
  for (int ri = 0; ri < 4; ++ri) {
    float4 o;
    o.x = acc[ri][0] + bv[0]; o.y = acc[ri][1] + bv[1];
    o.z = acc[ri][2] + bv[2]; o.w = acc[ri][3] + bv[3];
    *(float4*)(out + (size_t)(m0 + tr * 4 + ri) * 64 + tc * 4) = o;
  }
}

// ---------------- row L2-normalize (in place), wave per row ------------------
__global__ __launch_bounds__(256) void norm_rows(float* __restrict__ X)
{
  int row = blockIdx.x * 4 + (threadIdx.x >> 6);
  int lane = threadIdx.x & 63;
  float v = X[(size_t)row * 64 + lane];
  float ss = wred_sum(v * v);
  X[(size_t)row * 64 + lane] = v * rsqrtf(ss);
}

// ---------------- sim + per-chunk top-10 -------------------------------------
// grid (32, NCH), block 256.  thread -> row i; blockIdx.y -> j chunk
__global__ __launch_bounds__(256) void sim_topk(
    const float* __restrict__ Xn, float* __restrict__ pv, int* __restrict__ pi)
{
  __shared__ float4 Xs[TJ * 16];
  const int tid = threadIdx.x;
  const int i = blockIdx.x * 256 + tid;
  const bool act = i < N_ITEM;
  float4 xi[16];
  if (act) {
    const float4* xr = (const float4*)(Xn + (size_t)i * 64);
#pragma unroll
    for (int q = 0; q < 16; ++q) xi[q] = xr[q];
  }
  float vals[10]; int idxs[10];
#pragma unroll
  for (int t = 0; t < 10; ++t) { vals[t] = NEG_INF; idxs[t] = -1; }
  const int j0c = blockIdx.y * CHUNK;
  for (int jt = 0; jt < CHUNK; jt += TJ) {
    int tj = min(TJ, CHUNK - jt);
    __syncthreads();
    const float4* src = (const float4*)(Xn + (size_t)(j0c + jt) * 64);
    for (int p = tid; p < tj * 16; p += 256) Xs[p] = src[p];
    __syncthreads();
    if (act) {
      for (int jj = 0; jj < tj; ++jj) {
        const float4* xb = &Xs[jj * 16];
        float a0 = 0.f, a1 = 0.f, a2 = 0.f, a3 = 0.f;
#pragma unroll
        for (int q = 0; q < 16; ++q) {
          float4 b = xb[q];
          a0 += xi[q].x * b.x; a1 += xi[q].y * b.y;
          a2 += xi[q].z * b.z; a3 += xi[q].w * b.w;
        }
        float acc = (a0 + a1) + (a2 + a3);
        if (acc > vals[9]) {
          float cv = acc; int ci = j0c + jt + jj;
#pragma unroll
          for (int s = 0; s < 10; ++s) {
            if (cv > vals[s]) {
              float tv = vals[s]; int ti = idxs[s];
              vals[s] = cv; idxs[s] = ci; cv = tv; ci = ti;
            }
          }
        }
      }
    }
  }
  if (act) {
    size_t base = ((size_t)i * NCH + blockIdx.y) * 10;
#pragma unroll
    for (int t = 0; t < 10; ++t) { pv[base + t] = vals[t]; pi[base + t] = idxs[t]; }
  }
}

// ---------------- merge 320 partial candidates -> top-10 + dis ---------------
__global__ __launch_bounds__(256) void merge_topk(
    const float* __restrict__ pv, const int* __restrict__ pi,
    float* __restrict__ tv, int* __restrict__ tc, float* __restrict__ dis)
{
  int lane = threadIdx.x & 63;
  int row = blockIdx.x * 4 + (threadIdx.x >> 6);
  size_t base = (size_t)row * (NCH * 10);   // 320 = 5 * 64
  float cv[5]; int ci[5];
#pragma unroll
  for (int m = 0; m < 5; ++m) { cv[m] = pv[base + m * 64 + lane]; ci[m] = pi[base + m * 64 + lane]; }
  // bubble sort descending (5 elems)
#pragma unroll
  for (int a = 0; a < 4; ++a)
#pragma unroll
    for (int b = 0; b < 4 - a; ++b)
      if (cv[b + 1] > cv[b]) {
        float t = cv[b]; cv[b] = cv[b + 1]; cv[b + 1] = t;
        int ti = ci[b]; ci[b] = ci[b + 1]; ci[b + 1] = ti;
      }
  float deg = 0.f, keepv = 0.f; int keepc = 0;
  for (int t = 0; t < 10; ++t) {
    float v = cv[0]; int c = ci[0]; int wl = lane;
#pragma unroll
    for (int off = 32; off; off >>= 1) {
      float vo = __shfl_xor(v, off, 64);
      int co = __shfl_xor(c, off, 64);
      int wo = __shfl_xor(wl, off, 64);
      if (vo > v || (vo == v && wo < wl)) { v = vo; c = co; wl = wo; }
    }
    deg += v;
    if (lane == wl) {
#pragma unroll
      for (int m = 0; m < 4; ++m) { cv[m] = cv[m + 1]; ci[m] = ci[m + 1]; }
      cv[4] = NEG_INF; ci[4] = -1;
    }
    if (lane == t) { keepv = v; keepc = c; }
  }
  if (lane < 10) { tv[(size_t)row * 10 + lane] = keepv; tc[(size_t)row * 10 + lane] = keepc; }
  if (lane == 0) dis[row] = deg > 0.f ? rsqrtf(deg) : 0.f;
}

// ---------------- fused SPMM (new + orig neighbors) --------------------------
__global__ __launch_bounds__(256) void fused_spmm(
    const float* __restrict__ tv, const int* __restrict__ tc, const float* __restrict__ dis,
    const float* __restrict__ ow, const int* __restrict__ oc,
    const float* __restrict__ item_emb, float* __restrict__ agg)
{
  int lane = threadIdx.x & 63;
  int row = blockIdx.x * 4 + (threadIdx.x >> 6);
  float disr = dis[row];
  float acc = 0.f;
#pragma unroll
  for (int t = 0; t < 10; ++t) {
    int c = tc[(size_t)row * 10 + t];
    float w = 0.1f * disr * tv[(size_t)row * 10 + t] * dis[c];
    acc += w * item_emb[(size_t)c * 64 + lane];
  }
#pragma unroll
  for (int t = 0; t < 10; ++t) {
    int c = oc[(size_t)row * 10 + t];
    float w = 0.9f * ow[(size_t)row * 10 + t];
    acc += w * item_emb[(size_t)c * 64 + lane];
  }
  agg[(size_t)row * 64 + lane] = acc;
}

// ---------------- attention combine + h_norm ---------------------------------
__global__ __launch_bounds__(256) void attn_h(
    const float* __restrict__ ai, const float* __restrict__ at,
    const float* __restrict__ Wq1, const float* __restrict__ bq1,
    const float* __restrict__ wq2, float* __restrict__ hn)
{
  int lane = threadIdx.x & 63;
  int row = blockIdx.x * 4 + (threadIdx.x >> 6);
  const float* xi = ai + (size_t)row * 64;
  const float* xt = at + (size_t)row * 64;
  float y0 = bq1[lane], y1 = bq1[lane];
  for (int k = 0; k < 64; ++k) {
    float w = Wq1[k * 64 + lane];
    y0 += xi[k] * w;
    y1 += xt[k] * w;
  }
  float wq = wq2[lane];
  float s0 = wred_sum(tanhf(y0) * wq);
  float s1 = wred_sum(tanhf(y1) * wq);
  float m = fmaxf(s0, s1);
  float e0 = expf(s0 - m), e1 = expf(s1 - m);
  float inv = 1.f / (e0 + e1);
  float h = (e0 * inv) * xi[lane] + (e1 * inv) * xt[lane];
  float n2 = wred_sum(h * h);
  float nrm = fmaxf(sqrtf(n2), 1e-12f);
  hn[(size_t)row * 64 + lane] = h / nrm;
}

// ---------------- UI graph helpers -------------------------------------------
__global__ void ui_zero(int* degi, int* cursor)
{
  int n = blockIdx.x * 256 + threadIdx.x;
  if (n < N_NODE) { degi[n] = 0; cursor[n] = 0; }
}

__global__ void ui_count(const int* __restrict__ r, int* degi)
{
  int e = blockIdx.x * 256 + threadIdx.x;
  if (e < N_EDGE) atomicAdd(&degi[r[e]], 1);
}

__global__ __launch_bounds__(1024) void ui_scan(const int* __restrict__ degi, int* __restrict__ offs)
{
  __shared__ int sums[1024];
  int tid = threadIdx.x;
  int base_i = tid * 32;
  int s = 0;
  for (int k = 0; k < 32; ++k) { int idx = base_i + k; s += (idx < N_NODE) ? degi[idx] : 0; }
  sums[tid] = s;
  __syncthreads();
  for (int off = 1; off < 1024; off <<= 1) {
    int v = (tid >= off) ? sums[tid - off] : 0;
    __syncthreads();
    sums[tid] += v;
    __syncthreads();
  }
  int run = (tid == 0) ? 0 : sums[tid - 1];
  for (int k = 0; k < 32; ++k) {
    int idx = base_i + k;
    if (idx < N_NODE) { offs[idx] = run; run += degi[idx]; }
  }
  if (tid == 1023) offs[N_NODE] = run;
}

__global__ void ui_dis(const int* __restrict__ degi, float* __restrict__ dis)
{
  int n = blockIdx.x * 256 + threadIdx.x;
  if (n < N_NODE) dis[n] = degi[n] > 0 ? rsqrtf((float)degi[n]) : 0.f;
}

__global__ void ui_fill(const int* __restrict__ r, const int* __restrict__ c,
                        const int* __restrict__ offs, int* cursor, int* __restrict__ csr)
{
  int e = blockIdx.x * 256 + threadIdx.x;
  if (e < N_EDGE) {
    int rr = r[e];
    int pos = offs[rr] + atomicAdd(&cursor[rr], 1);
    csr[pos] = c[e];
  }
}

template <bool FIRST>
__global__ __launch_bounds__(256) void ui_prop(
    const float* __restrict__ in, const float* __restrict__ ue, const float* __restrict__ ie,
    float* __restrict__ out, const int* __restrict__ offs, const int* __restrict__ csr,
    const float* __restrict__ dis)
{
  int lane = threadIdx.x & 63;
  int row = blockIdx.x * 4 + (threadIdx.x >> 6);
  float acc = 0.f;
  int e0 = offs[row], e1 = offs[row + 1];
  for (int e = e0; e < e1; ++e) {
    int cc = csr[e];
    const float* src = FIRST
        ? (cc < N_USER ? ue + (size_t)cc * 64 : ie + (size_t)(cc - N_USER) * 64)
        : in + (size_t)cc * 64;
    acc += dis[cc] * src[lane];
  }
  out[(size_t)row * 64 + lane] = dis[row] * acc;
}

__global__ void ui_final(const float* __restrict__ ue, const float* __restrict__ ie,
                         const float* __restrict__ E1, const float* __restrict__ E2,
                         const float* __restrict__ hn, float* __restrict__ out)
{
  int idx = blockIdx.x * 256 + threadIdx.x;   // 0 .. 2047999
  int n = idx >> 6, d = idx & 63;
  float e0 = (n < N_USER) ? ue[idx] : ie[(size_t)(n - N_USER) * 64 + d];
  float v = (e0 + E1[idx] + E2[idx]) * (1.f / 3.f);
  if (n >= N_USER) v += hn[(size_t)(n - N_USER) * 64 + d];
  out[idx] = v;
}

// ---------------- host driver ------------------------------------------------
extern "C" void kernel_launch(void* const* d_in, const int* in_sizes, int n_in,
                              void* d_out, int out_size, void* d_ws, size_t ws_size,
                              hipStream_t stream)
{
  (void)in_sizes; (void)n_in; (void)out_size; (void)ws_size;
  const float* user_emb = (const float*)d_in[0];
  const float* item_emb = (const float*)d_in[1];
  const float* v_feat   = (const float*)d_in[2];
  const float* t_feat   = (const float*)d_in[3];
  const float* W_v      = (const float*)d_in[4];
  const float* b_v      = (const float*)d_in[5];
  const float* W_t      = (const float*)d_in[6];
  const float* b_t      = (const float*)d_in[7];
  const float* Wq1      = (const float*)d_in[8];
  const float* bq1      = (const float*)d_in[9];
  const float* wq2      = (const float*)d_in[10];
  const float* ow_i     = (const float*)d_in[11];
  const float* ow_t     = (const float*)d_in[12];
  const int*   eidx     = (const int*)d_in[13];
  const int*   oc_i     = (const int*)d_in[14];
  const int*   oc_t     = (const int*)d_in[15];
  float* out = (float*)d_out;

  char* wp = (char*)d_ws;
  auto alloc = [&](size_t bytes) -> void* {
    void* p = (void*)wp;
    wp += (bytes + 255) & ~(size_t)255;
    return p;
  };
  float* Xn    = (float*)alloc((size_t)N_ITEM * 64 * 4);
  float* pv    = (float*)alloc((size_t)N_ITEM * NCH * 10 * 4);
  int*   pi    = (int*)  alloc((size_t)N_ITEM * NCH * 10 * 4);
  float* tv_i  = (float*)alloc((size_t)N_ITEM * 10 * 4);
  int*   tc_i  = (int*)  alloc((size_t)N_ITEM * 10 * 4);
  float* dis_i = (float*)alloc((size_t)N_ITEM * 4);
  float* tv_t  = (float*)alloc((size_t)N_ITEM * 10 * 4);
  int*   tc_t  = (int*)  alloc((size_t)N_ITEM * 10 * 4);
  float* dis_t = (float*)alloc((size_t)N_ITEM * 4);
  float* agg_i = (float*)alloc((size_t)N_ITEM * 64 * 4);
  float* agg_t = (float*)alloc((size_t)N_ITEM * 64 * 4);
  float* hn    = (float*)alloc((size_t)N_ITEM * 64 * 4);
  int*   degi  = (int*)  alloc((size_t)N_NODE * 4);
  int*   curs  = (int*)  alloc((size_t)N_NODE * 4);
  int*   offs  = (int*)  alloc((size_t)(N_NODE + 1) * 4);
  float* disui = (float*)alloc((size_t)N_NODE * 4);
  int*   csr   = (int*)  alloc((size_t)N_EDGE * 4);
  // ego layer buffers alias the (dead-by-then) partial-topk buffers
  float* E1 = pv;              // needs 2,048,000 floats <= 2,560,000
  float* E2 = (float*)pi;

  // ---- image modality ----
  gemm_bias64<<<125, 256, 0, stream>>>(v_feat, W_v, b_v, Xn, 2048);
  norm_rows<<<2000, 256, 0, stream>>>(Xn);
  sim_topk<<<dim3(32, NCH), 256, 0, stream>>>(Xn, pv, pi);
  merge_topk<<<2000, 256, 0, stream>>>(pv, pi, tv_i, tc_i, dis_i);
  // ---- text modality ----
  gemm_bias64<<<125, 256, 0, stream>>>(t_feat, W_t, b_t, Xn, 384);
  norm_rows<<<2000, 256, 0, stream>>>(Xn);
  sim_topk<<<dim3(32, NCH), 256, 0, stream>>>(Xn, pv, pi);
  merge_topk<<<2000, 256, 0, stream>>>(pv, pi, tv_t, tc_t, dis_t);
  // ---- fused SPMM + attention ----
  fused_spmm<<<2000, 256, 0, stream>>>(tv_i, tc_i, dis_i, ow_i, oc_i, item_emb, agg_i);
  fused_spmm<<<2000, 256, 0, stream>>>(tv_t, tc_t, dis_t, ow_t, oc_t, item_emb, agg_t);
  attn_h<<<2000, 256, 0, stream>>>(agg_i, agg_t, Wq1, bq1, wq2, hn);
  // ---- user-item graph ----
  ui_zero<<<125, 256, 0, stream>>>(degi, curs);
  ui_count<<<N_EDGE / 256, 256, 0, stream>>>(eidx, degi);
  ui_scan<<<1, 1024, 0, stream>>>(degi, offs);
  ui_dis<<<125, 256, 0, stream>>>(degi, disui);
  ui_fill<<<N_EDGE / 256, 256, 0, stream>>>(eidx, eidx + N_EDGE, offs, curs, csr);
  ui_prop<true><<<8000, 256, 0, stream>>>(nullptr, user_emb, item_emb, E1, offs, csr, disui);
  ui_prop<false><<<8000, 256, 0, stream>>>(E1, user_emb, item_emb, E2, offs, csr, disui);
  ui_final<<<8000, 256, 0, stream>>>(user_emb, item_emb, E1, E2, hn, out);
}

// Round 2
// 1271.889 us; speedup vs baseline: 1.1119x; 1.1119x over previous
//
#include <hip/hip_runtime.h>
#include <math.h>

#define N_USER 24000
#define N_ITEM 8000
#define N_NODE 32000
#define N_EDGE 800000
#define NJC    4           // j-chunks for sim/topk
#define JCH    2000        // N_ITEM / NJC
#define PJ     128         // j-panel rows staged in LDS
#define NEG_INF -1e30f

typedef __attribute__((ext_vector_type(8))) short bf16x8;
typedef __attribute__((ext_vector_type(4))) float f32x4;

__device__ __forceinline__ float wred_sum(float v) {
#pragma unroll
  for (int off = 32; off; off >>= 1) v += __shfl_xor(v, off, 64);
  return v;
}

__device__ __forceinline__ unsigned short f2bf(float f) {
  unsigned int u = __float_as_uint(f);
  unsigned int r = (u + 0x7fffu + ((u >> 16) & 1u)) >> 16;
  return (unsigned short)r;
}
__device__ __forceinline__ float bf2f(unsigned short h) {
  return __uint_as_float(((unsigned int)h) << 16);
}

#define INSERT10(vv, jj, V, I)                          \
  if ((vv) > V[9]) {                                    \
    float cv_ = (vv); int ci_ = (jj);                   \
    _Pragma("unroll")                                   \
    for (int s_ = 0; s_ < 10; ++s_) {                   \
      if (cv_ > V[s_]) {                                \
        float tv_ = V[s_]; int ti_ = I[s_];             \
        V[s_] = cv_; I[s_] = ci_; cv_ = tv_; ci_ = ti_; \
      }                                                 \
    }                                                   \
  }

// ---------------- projection GEMM partial: P[chunk] = X[:, k0:k0+Klen] @ W[k0:k0+Klen, :]
__global__ __launch_bounds__(256) void gemm64(
    const float* __restrict__ X, const float* __restrict__ W,
    float* __restrict__ P, int K, int Klen)
{
  __shared__ float As[32 * 64];   // As[k][r]
  __shared__ float Bs[32 * 64];   // Bs[k][n]
  const int tid = threadIdx.x;
  const int m0 = blockIdx.x * 64;
  const int kc0 = blockIdx.y * Klen;
  float* out = P + (size_t)blockIdx.y * N_ITEM * 64;
  const int tr = tid >> 4, tc = tid & 15;
  float acc[4][4] = {};
  for (int k0 = kc0; k0 < kc0 + Klen; k0 += 32) {
    __syncthreads();
#pragma unroll
    for (int l = 0; l < 2; ++l) {
      int f4 = tid + l * 256;
      int r = f4 >> 3, kq = f4 & 7;        // A: 64 rows x 8 float4
      float4 a = *(const float4*)(X + (size_t)(m0 + r) * K + k0 + kq * 4);
      As[(kq * 4 + 0) * 64 + r] = a.x;
      As[(kq * 4 + 1) * 64 + r] = a.y;
      As[(kq * 4 + 2) * 64 + r] = a.z;
      As[(kq * 4 + 3) * 64 + r] = a.w;
      int kb = f4 >> 4, nq = f4 & 15;      // B: 32 rows x 16 float4
      *(float4*)(Bs + kb * 64 + nq * 4) =
          *(const float4*)(W + (size_t)(k0 + kb) * 64 + nq * 4);
    }
    __syncthreads();
#pragma unroll
    for (int k = 0; k < 32; ++k) {
      float4 a4 = *(const float4*)(As + k * 64 + tr * 4);
      float4 b4 = *(const float4*)(Bs + k * 64 + tc * 4);
      float av[4] = {a4.x, a4.y, a4.z, a4.w};
      float bv[4] = {b4.x, b4.y, b4.z, b4.w};
#pragma unroll
      for (int ri = 0; ri < 4; ++ri)
#pragma unroll
        for (int ci = 0; ci < 4; ++ci) acc[ri][ci] += av[ri] * bv[ci];
    }
  }
#pragma unroll
  for (int ri = 0; ri < 4; ++ri) {
    float4 o;
    o.x = acc[ri][0]; o.y = acc[ri][1]; o.z = acc[ri][2]; o.w = acc[ri][3];
    *(float4*)(out + (size_t)(m0 + tr * 4 + ri) * 64 + tc * 4) = o;
  }
}

// ---------------- sum partials + bias, L2-normalize, split to bf16 hi/lo -----
__global__ __launch_bounds__(256) void norm_split(
    const float* __restrict__ P, const float* __restrict__ bias,
    unsigned short* __restrict__ Xh, unsigned short* __restrict__ Xl)
{
  int row = blockIdx.x * 4 + (threadIdx.x >> 6);
  int lane = threadIdx.x & 63;
  size_t o = (size_t)row * 64 + lane;
  float v = P[o] + P[(size_t)N_ITEM * 64 + o] + bias[lane];
  float ss = wred_sum(v * v);
  float xn = v * rsqrtf(ss);
  unsigned short hi = f2bf(xn);
  Xh[o] = hi;
  Xl[o] = f2bf(xn - bf2f(hi));
}

// ---------------- MFMA sim + fused per-lane top-10 ---------------------------
// grid (63, NJC), block 256 (4 waves). Block: 128 i-rows; wave: 32 i (2x16).
// A operand = j-rows (from LDS panel), B operand = i-rows -> C[j_loc, i_loc].
__global__ __launch_bounds__(256) void sim_topk_mfma(
    const unsigned short* __restrict__ Xh, const unsigned short* __restrict__ Xl,
    float* __restrict__ pv, int* __restrict__ pi)
{
  __shared__ unsigned short ldsbuf[2 * PJ * 64];   // 32 KiB: hi panel + lo panel
  char* ldsH = (char*)ldsbuf;
  char* ldsL = ldsH + PJ * 64 * 2;

  const int tid = threadIdx.x;
  const int l = tid & 63;
  const int wid = tid >> 6;
  const int ib = blockIdx.x * 128 + wid * 32;
  const int j0c = blockIdx.y * JCH;

  // B-fragments (i side), loaded once. s = i-subtile (0/1), kh = K-half.
  bf16x8 bh[2][2], bl[2][2];
#pragma unroll
  for (int s = 0; s < 2; ++s) {
    int irow = ib + s * 16 + (l & 15);
    if (irow > N_ITEM - 1) irow = N_ITEM - 1;
    int ksl = (l >> 4) * 8;
#pragma unroll
    for (int kh = 0; kh < 2; ++kh) {
      bh[s][kh] = *(const bf16x8*)(Xh + (size_t)irow * 64 + kh * 32 + ksl);
      bl[s][kh] = *(const bf16x8*)(Xl + (size_t)irow * 64 + kh * 32 + ksl);
    }
  }

  float vals0[10], vals1[10]; int idx0[10], idx1[10];
#pragma unroll
  for (int t = 0; t < 10; ++t) {
    vals0[t] = NEG_INF; idx0[t] = -1; vals1[t] = NEG_INF; idx1[t] = -1;
  }

  const int NPANEL = (JCH + PJ - 1) / PJ;        // 16
  const int NTILE = JCH / 16;                    // 125
  for (int p = 0; p < NPANEL; ++p) {
    __syncthreads();
    // stage panel p (hi+lo) with XOR swizzle: byte ^= (row&7)<<4
#pragma unroll
    for (int s = 0; s < 4; ++s) {
      int u = tid + s * 256;                     // 16B units, 0..1023
      int row = u >> 3;
      int cb = (u & 7) * 16;                     // col byte 0..112
      int gr = j0c + p * PJ + row;
      if (gr > N_ITEM - 1) gr = N_ITEM - 1;
      int4 vh = *(const int4*)(Xh + (size_t)gr * 64 + (cb >> 1));
      int4 vl = *(const int4*)(Xl + (size_t)gr * 64 + (cb >> 1));
      int bo = (row * 128 + cb) ^ ((row & 7) << 4);
      *(int4*)(ldsH + bo) = vh;
      *(int4*)(ldsL + bo) = vl;
    }
    __syncthreads();
    int t0 = p * (PJ / 16);
    int t1 = min(t0 + PJ / 16, NTILE);
    for (int tp = t0; tp < t1; ++tp) {
      int jr = (tp - t0) * 16 + (l & 15);        // A row in panel
      int sw = (jr & 7) << 4;
      int rb = jr * 128 + ((l >> 4) << 4);
      bf16x8 ah0 = *(bf16x8*)(ldsH + (rb ^ sw));
      bf16x8 ah1 = *(bf16x8*)(ldsH + ((rb + 64) ^ sw));
      bf16x8 al0 = *(bf16x8*)(ldsL + (rb ^ sw));
      bf16x8 al1 = *(bf16x8*)(ldsL + ((rb + 64) ^ sw));
      int jg0 = j0c + tp * 16 + ((l >> 4) << 2);
      {
        f32x4 acc = {0.f, 0.f, 0.f, 0.f};
        acc = __builtin_amdgcn_mfma_f32_16x16x32_bf16(ah0, bh[0][0], acc, 0, 0, 0);
        acc = __builtin_amdgcn_mfma_f32_16x16x32_bf16(ah1, bh[0][1], acc, 0, 0, 0);
        acc = __builtin_amdgcn_mfma_f32_16x16x32_bf16(ah0, bl[0][0], acc, 0, 0, 0);
        acc = __builtin_amdgcn_mfma_f32_16x16x32_bf16(ah1, bl[0][1], acc, 0, 0, 0);
        acc = __builtin_amdgcn_mfma_f32_16x16x32_bf16(al0, bh[0][0], acc, 0, 0, 0);
        acc = __builtin_amdgcn_mfma_f32_16x16x32_bf16(al1, bh[0][1], acc, 0, 0, 0);
#pragma unroll
        for (int r = 0; r < 4; ++r) {
          float v = acc[r]; int jj = jg0 + r;
          INSERT10(v, jj, vals0, idx0);
        }
      }
      {
        f32x4 acc = {0.f, 0.f, 0.f, 0.f};
        acc = __builtin_amdgcn_mfma_f32_16x16x32_bf16(ah0, bh[1][0], acc, 0, 0, 0);
        acc = __builtin_amdgcn_mfma_f32_16x16x32_bf16(ah1, bh[1][1], acc, 0, 0, 0);
        acc = __builtin_amdgcn_mfma_f32_16x16x32_bf16(ah0, bl[1][0], acc, 0, 0, 0);
        acc = __builtin_amdgcn_mfma_f32_16x16x32_bf16(ah1, bl[1][1], acc, 0, 0, 0);
        acc = __builtin_amdgcn_mfma_f32_16x16x32_bf16(al0, bh[1][0], acc, 0, 0, 0);
        acc = __builtin_amdgcn_mfma_f32_16x16x32_bf16(al1, bh[1][1], acc, 0, 0, 0);
#pragma unroll
        for (int r = 0; r < 4; ++r) {
          float v = acc[r]; int jj = jg0 + r;
          INSERT10(v, jj, vals1, idx1);
        }
      }
    }
  }

  // store per-lane top-10: layout [i][chunk][g][10], g = lane>>4
  int g = l >> 4;
  {
    int i = ib + (l & 15);
    if (i < N_ITEM) {
      size_t base = (((size_t)i * NJC + blockIdx.y) * 4 + g) * 10;
#pragma unroll
      for (int t = 0; t < 10; ++t) { pv[base + t] = vals0[t]; pi[base + t] = idx0[t]; }
    }
  }
  {
    int i = ib + 16 + (l & 15);
    if (i < N_ITEM) {
      size_t base = (((size_t)i * NJC + blockIdx.y) * 4 + g) * 10;
#pragma unroll
      for (int t = 0; t < 10; ++t) { pv[base + t] = vals1[t]; pi[base + t] = idx1[t]; }
    }
  }
}

// ---------------- merge 160 partial candidates -> top-10 + dis ---------------
__global__ __launch_bounds__(256) void merge_topk(
    const float* __restrict__ pv, const int* __restrict__ pi,
    float* __restrict__ tv, int* __restrict__ tc, float* __restrict__ dis)
{
  int lane = threadIdx.x & 63;
  int row = blockIdx.x * 4 + (threadIdx.x >> 6);
  size_t base = (size_t)row * (NJC * 4 * 10);    // 160 = 64 + 64 + 32
  float cv[3]; int ci[3];
  cv[0] = pv[base + lane];        ci[0] = pi[base + lane];
  cv[1] = pv[base + 64 + lane];   ci[1] = pi[base + 64 + lane];
  if (lane < 32) { cv[2] = pv[base + 128 + lane]; ci[2] = pi[base + 128 + lane]; }
  else           { cv[2] = NEG_INF; ci[2] = 0x7fffffff; }
  float deg = 0.f, keepv = 0.f; int keepc = 0;
  for (int t = 0; t < 10; ++t) {
    // local max of 3 with smaller-idx tie-break
    float mv = cv[0]; int mi = ci[0]; int slot = 0;
    if (cv[1] > mv || (cv[1] == mv && ci[1] < mi)) { mv = cv[1]; mi = ci[1]; slot = 1; }
    if (cv[2] > mv || (cv[2] == mv && ci[2] < mi)) { mv = cv[2]; mi = ci[2]; slot = 2; }
    float v = mv; int c = mi;
#pragma unroll
    for (int off = 32; off; off >>= 1) {
      float vo = __shfl_xor(v, off, 64);
      int co = __shfl_xor(c, off, 64);
      if (vo > v || (vo == v && co < c)) { v = vo; c = co; }
    }
    deg += v;
    if (mv == v && mi == c) {   // this lane owned the winner
      if (slot == 0) { cv[0] = NEG_INF; ci[0] = 0x7fffffff; }
      else if (slot == 1) { cv[1] = NEG_INF; ci[1] = 0x7fffffff; }
      else { cv[2] = NEG_INF; ci[2] = 0x7fffffff; }
    }
    if (lane == t) { keepv = v; keepc = c; }
  }
  if (lane < 10) { tv[(size_t)row * 10 + lane] = keepv; tc[(size_t)row * 10 + lane] = keepc; }
  if (lane == 0) dis[row] = deg > 0.f ? rsqrtf(deg) : 0.f;
}

// ---------------- fused SPMM (new + orig neighbors) --------------------------
__global__ __launch_bounds__(256) void fused_spmm(
    const float* __restrict__ tv, const int* __restrict__ tc, const float* __restrict__ dis,
    const float* __restrict__ ow, const int* __restrict__ oc,
    const float* __restrict__ item_emb, float* __restrict__ agg)
{
  int lane = threadIdx.x & 63;
  int row = blockIdx.x * 4 + (threadIdx.x >> 6);
  float disr = dis[row];
  float acc = 0.f;
#pragma unroll
  for (int t = 0; t < 10; ++t) {
    int c = tc[(size_t)row * 10 + t];
    float w = 0.1f * disr * tv[(size_t)row * 10 + t] * dis[c];
    acc += w * item_emb[(size_t)c * 64 + lane];
  }
#pragma unroll
  for (int t = 0; t < 10; ++t) {
    int c = oc[(size_t)row * 10 + t];
    float w = 0.9f * ow[(size_t)row * 10 + t];
    acc += w * item_emb[(size_t)c * 64 + lane];
  }
  agg[(size_t)row * 64 + lane] = acc;
}

// ---------------- attention combine + h_norm ---------------------------------
__global__ __launch_bounds__(256) void attn_h(
    const float* __restrict__ ai, const float* __restrict__ at,
    const float* __restrict__ Wq1, const float* __restrict__ bq1,
    const float* __restrict__ wq2, float* __restrict__ hn)
{
  int lane = threadIdx.x & 63;
  int row = blockIdx.x * 4 + (threadIdx.x >> 6);
  const float* xi = ai + (size_t)row * 64;
  const float* xt = at + (size_t)row * 64;
  float y0 = bq1[lane], y1 = bq1[lane];
  for (int k = 0; k < 64; ++k) {
    float w = Wq1[k * 64 + lane];
    y0 += xi[k] * w;
    y1 += xt[k] * w;
  }
  float wq = wq2[lane];
  float s0 = wred_sum(tanhf(y0) * wq);
  float s1 = wred_sum(tanhf(y1) * wq);
  float m = fmaxf(s0, s1);
  float e0 = expf(s0 - m), e1 = expf(s1 - m);
  float inv = 1.f / (e0 + e1);
  float h = (e0 * inv) * xi[lane] + (e1 * inv) * xt[lane];
  float n2 = wred_sum(h * h);
  float nrm = fmaxf(sqrtf(n2), 1e-12f);
  hn[(size_t)row * 64 + lane] = h / nrm;
}

// ---------------- UI graph helpers -------------------------------------------
__global__ void ui_zero(int* degi, int* cursor)
{
  int n = blockIdx.x * 256 + threadIdx.x;
  if (n < N_NODE) { degi[n] = 0; cursor[n] = 0; }
}

__global__ void ui_count(const int* __restrict__ r, int* degi)
{
  int e = blockIdx.x * 256 + threadIdx.x;
  if (e < N_EDGE) atomicAdd(&degi[r[e]], 1);
}

__global__ __launch_bounds__(1024) void ui_scan(const int* __restrict__ degi, int* __restrict__ offs)
{
  __shared__ int sums[1024];
  int tid = threadIdx.x;
  int base_i = tid * 32;
  int s = 0;
  for (int k = 0; k < 32; ++k) { int idx = base_i + k; s += (idx < N_NODE) ? degi[idx] : 0; }
  sums[tid] = s;
  __syncthreads();
  for (int off = 1; off < 1024; off <<= 1) {
    int v = (tid >= off) ? sums[tid - off] : 0;
    __syncthreads();
    sums[tid] += v;
    __syncthreads();
  }
  int run = (tid == 0) ? 0 : sums[tid - 1];
  for (int k = 0; k < 32; ++k) {
    int idx = base_i + k;
    if (idx < N_NODE) { offs[idx] = run; run += degi[idx]; }
  }
  if (tid == 1023) offs[N_NODE] = run;
}

__global__ void ui_dis(const int* __restrict__ degi, float* __restrict__ dis)
{
  int n = blockIdx.x * 256 + threadIdx.x;
  if (n < N_NODE) dis[n] = degi[n] > 0 ? rsqrtf((float)degi[n]) : 0.f;
}

__global__ void ui_fill(const int* __restrict__ r, const int* __restrict__ c,
                        const int* __restrict__ offs, int* cursor, int* __restrict__ csr)
{
  int e = blockIdx.x * 256 + threadIdx.x;
  if (e < N_EDGE) {
    int rr = r[e];
    int pos = offs[rr] + atomicAdd(&cursor[rr], 1);
    csr[pos] = c[e];
  }
}

template <bool FIRST>
__global__ __launch_bounds__(256) void ui_prop(
    const float* __restrict__ in, const float* __restrict__ ue, const float* __restrict__ ie,
    float* __restrict__ out, const int* __restrict__ offs, const int* __restrict__ csr,
    const float* __restrict__ dis)
{
  int lane = threadIdx.x & 63;
  int row = blockIdx.x * 4 + (threadIdx.x >> 6);
  float acc = 0.f;
  int e0 = offs[row], e1 = offs[row + 1];
  for (int e = e0; e < e1; ++e) {
    int cc = csr[e];
    const float* src = FIRST
        ? (cc < N_USER ? ue + (size_t)cc * 64 : ie + (size_t)(cc - N_USER) * 64)
        : in + (size_t)cc * 64;
    acc += dis[cc] * src[lane];
  }
  out[(size_t)row * 64 + lane] = dis[row] * acc;
}

__global__ void ui_final(const float* __restrict__ ue, const float* __restrict__ ie,
                         const float* __restrict__ E1, const float* __restrict__ E2,
                         const float* __restrict__ hn, float* __restrict__ out)
{
  int idx = blockIdx.x * 256 + threadIdx.x;   // 0 .. 2047999
  int n = idx >> 6, d = idx & 63;
  float e0 = (n < N_USER) ? ue[idx] : ie[(size_t)(n - N_USER) * 64 + d];
  float v = (e0 + E1[idx] + E2[idx]) * (1.f / 3.f);
  if (n >= N_USER) v += hn[(size_t)(n - N_USER) * 64 + d];
  out[idx] = v;
}

// ---------------- host driver ------------------------------------------------
extern "C" void kernel_launch(void* const* d_in, const int* in_sizes, int n_in,
                              void* d_out, int out_size, void* d_ws, size_t ws_size,
                              hipStream_t stream)
{
  (void)in_sizes; (void)n_in; (void)out_size; (void)ws_size;
  const float* user_emb = (const float*)d_in[0];
  const float* item_emb = (const float*)d_in[1];
  const float* v_feat   = (const float*)d_in[2];
  const float* t_feat   = (const float*)d_in[3];
  const float* W_v      = (const float*)d_in[4];
  const float* b_v      = (const float*)d_in[5];
  const float* W_t      = (const float*)d_in[6];
  const float* b_t      = (const float*)d_in[7];
  const float* Wq1      = (const float*)d_in[8];
  const float* bq1      = (const float*)d_in[9];
  const float* wq2      = (const float*)d_in[10];
  const float* ow_i     = (const float*)d_in[11];
  const float* ow_t     = (const float*)d_in[12];
  const int*   eidx     = (const int*)d_in[13];
  const int*   oc_i     = (const int*)d_in[14];
  const int*   oc_t     = (const int*)d_in[15];
  float* out = (float*)d_out;

  char* wp = (char*)d_ws;
  auto alloc = [&](size_t bytes) -> void* {
    void* p = (void*)wp;
    wp += (bytes + 255) & ~(size_t)255;
    return p;
  };
  // two big buffers: partial-topk first, then aliased as ego layer buffers
  float* BIG0 = (float*)alloc((size_t)N_NODE * 64 * 4 + 1024);   // >= 8.192 MB
  float* BIG1 = (float*)alloc((size_t)N_NODE * 64 * 4 + 1024);
  float* pv = BIG0;              // needs 8000*160*4 = 5.12 MB
  int*   pi = (int*)BIG1;
  float* E1 = BIG0;
  float* E2 = BIG1;

  float*          Pp  = (float*)alloc((size_t)2 * N_ITEM * 64 * 4);  // 2 k-chunk partials
  unsigned short* Xh  = (unsigned short*)alloc((size_t)N_ITEM * 64 * 2);
  unsigned short* Xl  = (unsigned short*)alloc((size_t)N_ITEM * 64 * 2);
  float* tv_i  = (float*)alloc((size_t)N_ITEM * 10 * 4);
  int*   tc_i  = (int*)  alloc((size_t)N_ITEM * 10 * 4);
  float* dis_i = (float*)alloc((size_t)N_ITEM * 4);
  float* tv_t  = (float*)alloc((size_t)N_ITEM * 10 * 4);
  int*   tc_t  = (int*)  alloc((size_t)N_ITEM * 10 * 4);
  float* dis_t = (float*)alloc((size_t)N_ITEM * 4);
  float* agg_i = (float*)alloc((size_t)N_ITEM * 64 * 4);
  float* agg_t = (float*)alloc((size_t)N_ITEM * 64 * 4);
  float* hn    = (float*)alloc((size_t)N_ITEM * 64 * 4);
  int*   degi  = (int*)  alloc((size_t)N_NODE * 4);
  int*   curs  = (int*)  alloc((size_t)N_NODE * 4);
  int*   offs  = (int*)  alloc((size_t)(N_NODE + 1) * 4);
  float* disui = (float*)alloc((size_t)N_NODE * 4);
  int*   csr   = (int*)  alloc((size_t)N_EDGE * 4);

  // ---- image modality ----
  gemm64<<<dim3(125, 2), 256, 0, stream>>>(v_feat, W_v, Pp, 2048, 1024);
  norm_split<<<2000, 256, 0, stream>>>(Pp, b_v, Xh, Xl);
  sim_topk_mfma<<<dim3(63, NJC), 256, 0, stream>>>(Xh, Xl, pv, pi);
  merge_topk<<<2000, 256, 0, stream>>>(pv, pi, tv_i, tc_i, dis_i);
  // ---- text modality ----
  gemm64<<<dim3(125, 2), 256, 0, stream>>>(t_feat, W_t, Pp, 384, 192);
  norm_split<<<2000, 256, 0, stream>>>(Pp, b_t, Xh, Xl);
  sim_topk_mfma<<<dim3(63, NJC), 256, 0, stream>>>(Xh, Xl, pv, pi);
  merge_topk<<<2000, 256, 0, stream>>>(pv, pi, tv_t, tc_t, dis_t);
  // ---- fused SPMM + attention ----
  fused_spmm<<<2000, 256, 0, stream>>>(tv_i, tc_i, dis_i, ow_i, oc_i, item_emb, agg_i);
  fused_spmm<<<2000, 256, 0, stream>>>(tv_t, tc_t, dis_t, ow_t, oc_t, item_emb, agg_t);
  attn_h<<<2000, 256, 0, stream>>>(agg_i, agg_t, Wq1, bq1, wq2, hn);
  // ---- user-item graph ----
  ui_zero<<<125, 256, 0, stream>>>(degi, curs);
  ui_count<<<N_EDGE / 256, 256, 0, stream>>>(eidx, degi);
  ui_scan<<<1, 1024, 0, stream>>>(degi, offs);
  ui_dis<<<125, 256, 0, stream>>>(degi, disui);
  ui_fill<<<N_EDGE / 256, 256, 0, stream>>>(eidx, eidx + N_EDGE, offs, curs, csr);
  ui_prop<true><<<8000, 256, 0, stream>>>(nullptr, user_emb, item_emb, E1, offs, csr, disui);
  ui_prop<false><<<8000, 256, 0, stream>>>(E1, user_emb, item_emb, E2, offs, csr, disui);
  ui_final<<<8000, 256, 0, stream>>>(user_emb, item_emb, E1, E2, hn, out);
}

// Round 3
// 698.319 us; speedup vs baseline: 2.0251x; 1.8214x over previous
//
#include <hip/hip_runtime.h>
#include <math.h>

#define N_USER 24000
#define N_ITEM 8000
#define N_NODE 32000
#define N_EDGE 800000
#define NJC    16          // j-chunks for sim/topk
#define JCH    500         // real j per chunk (padded scan to 512)
#define PJ     128         // j-panel rows staged in LDS
#define NEG_INF -1e30f

typedef __attribute__((ext_vector_type(8))) short bf16x8;
typedef __attribute__((ext_vector_type(4))) float f32x4;

__device__ __forceinline__ float wred_sum(float v) {
#pragma unroll
  for (int off = 32; off; off >>= 1) v += __shfl_xor(v, off, 64);
  return v;
}

__device__ __forceinline__ unsigned short f2bf(float f) {
  unsigned int u = __float_as_uint(f);
  unsigned int r = (u + 0x7fffu + ((u >> 16) & 1u)) >> 16;
  return (unsigned short)r;
}
__device__ __forceinline__ float bf2f(unsigned short h) {
  return __uint_as_float(((unsigned int)h) << 16);
}

#define INSERT10(vv, jj, V, I)                          \
  if ((vv) > V[9]) {                                    \
    float cv_ = (vv); int ci_ = (jj);                   \
    _Pragma("unroll")                                   \
    for (int s_ = 0; s_ < 10; ++s_) {                   \
      if (cv_ > V[s_]) {                                \
        float tv_ = V[s_]; int ti_ = I[s_];             \
        V[s_] = cv_; I[s_] = ci_; cv_ = tv_; ci_ = ti_; \
      }                                                 \
    }                                                   \
  }

// ---------------- projection GEMM partial: P[chunk] = X[:, k0:k0+Klen] @ W[k0:k0+Klen, :]
__global__ __launch_bounds__(256) void gemm64(
    const float* __restrict__ X, const float* __restrict__ W,
    float* __restrict__ P, int K, int Klen)
{
  __shared__ float As[32 * 64];   // As[k][r]
  __shared__ float Bs[32 * 64];   // Bs[k][n]
  const int tid = threadIdx.x;
  const int m0 = blockIdx.x * 64;
  const int kc0 = blockIdx.y * Klen;
  float* out = P + (size_t)blockIdx.y * N_ITEM * 64;
  const int tr = tid >> 4, tc = tid & 15;
  float acc[4][4] = {};
  for (int k0 = kc0; k0 < kc0 + Klen; k0 += 32) {
    __syncthreads();
#pragma unroll
    for (int l = 0; l < 2; ++l) {
      int f4 = tid + l * 256;
      int r = f4 >> 3, kq = f4 & 7;        // A: 64 rows x 8 float4
      float4 a = *(const float4*)(X + (size_t)(m0 + r) * K + k0 + kq * 4);
      As[(kq * 4 + 0) * 64 + r] = a.x;
      As[(kq * 4 + 1) * 64 + r] = a.y;
      As[(kq * 4 + 2) * 64 + r] = a.z;
      As[(kq * 4 + 3) * 64 + r] = a.w;
      int kb = f4 >> 4, nq = f4 & 15;      // B: 32 rows x 16 float4
      *(float4*)(Bs + kb * 64 + nq * 4) =
          *(const float4*)(W + (size_t)(k0 + kb) * 64 + nq * 4);
    }
    __syncthreads();
#pragma unroll
    for (int k = 0; k < 32; ++k) {
      float4 a4 = *(const float4*)(As + k * 64 + tr * 4);
      float4 b4 = *(const float4*)(Bs + k * 64 + tc * 4);
      float av[4] = {a4.x, a4.y, a4.z, a4.w};
      float bv[4] = {b4.x, b4.y, b4.z, b4.w};
#pragma unroll
      for (int ri = 0; ri < 4; ++ri)
#pragma unroll
        for (int ci = 0; ci < 4; ++ci) acc[ri][ci] += av[ri] * bv[ci];
    }
  }
#pragma unroll
  for (int ri = 0; ri < 4; ++ri) {
    float4 o;
    o.x = acc[ri][0]; o.y = acc[ri][1]; o.z = acc[ri][2]; o.w = acc[ri][3];
    *(float4*)(out + (size_t)(m0 + tr * 4 + ri) * 64 + tc * 4) = o;
  }
}

// ---------------- sum partials + bias, L2-normalize, split to bf16 hi/lo -----
__global__ __launch_bounds__(256) void norm_split(
    const float* __restrict__ P, const float* __restrict__ bias,
    unsigned short* __restrict__ Xh, unsigned short* __restrict__ Xl)
{
  int row = blockIdx.x * 4 + (threadIdx.x >> 6);
  int lane = threadIdx.x & 63;
  size_t o = (size_t)row * 64 + lane;
  float v = P[o] + P[(size_t)N_ITEM * 64 + o] + bias[lane];
  float ss = wred_sum(v * v);
  float xn = v * rsqrtf(ss);
  unsigned short hi = f2bf(xn);
  Xh[o] = hi;
  Xl[o] = f2bf(xn - bf2f(hi));
}

// ---------------- MFMA sim + fused per-lane top-10 ---------------------------
// grid (63, NJC), block 256 (4 waves). Block: 128 i-rows; wave: 32 i (2x16).
// A operand = j-rows (from LDS panel), B operand = i-rows -> C[j_loc, i_loc].
__global__ __launch_bounds__(256) void sim_topk_mfma(
    const unsigned short* __restrict__ Xh, const unsigned short* __restrict__ Xl,
    float* __restrict__ pv, int* __restrict__ pi)
{
  __shared__ unsigned short ldsbuf[2 * PJ * 64];   // 32 KiB: hi panel + lo panel
  char* ldsH = (char*)ldsbuf;
  char* ldsL = ldsH + PJ * 64 * 2;

  const int tid = threadIdx.x;
  const int l = tid & 63;
  const int wid = tid >> 6;
  const int ib = blockIdx.x * 128 + wid * 32;
  const int j0c = blockIdx.y * JCH;
  const int jlim = j0c + JCH;

  // B-fragments (i side), loaded once. s = i-subtile (0/1), kh = K-half.
  bf16x8 bh[2][2], bl[2][2];
#pragma unroll
  for (int s = 0; s < 2; ++s) {
    int irow = ib + s * 16 + (l & 15);
    if (irow > N_ITEM - 1) irow = N_ITEM - 1;
    int ksl = (l >> 4) * 8;
#pragma unroll
    for (int kh = 0; kh < 2; ++kh) {
      bh[s][kh] = *(const bf16x8*)(Xh + (size_t)irow * 64 + kh * 32 + ksl);
      bl[s][kh] = *(const bf16x8*)(Xl + (size_t)irow * 64 + kh * 32 + ksl);
    }
  }

  float vals0[10], vals1[10]; int idx0[10], idx1[10];
#pragma unroll
  for (int t = 0; t < 10; ++t) {
    vals0[t] = NEG_INF; idx0[t] = -1; vals1[t] = NEG_INF; idx1[t] = -1;
  }

  // 4 panels of 128 rows cover the padded 512-row chunk
  for (int p = 0; p < 4; ++p) {
    __syncthreads();
    // stage panel p (hi+lo) with XOR swizzle: byte ^= (row&7)<<4
#pragma unroll
    for (int s = 0; s < 4; ++s) {
      int u = tid + s * 256;                     // 16B units, 0..1023
      int row = u >> 3;
      int cb = (u & 7) * 16;                     // col byte 0..112
      int gr = j0c + p * PJ + row;
      if (gr > N_ITEM - 1) gr = N_ITEM - 1;
      int4 vh = *(const int4*)(Xh + (size_t)gr * 64 + (cb >> 1));
      int4 vl = *(const int4*)(Xl + (size_t)gr * 64 + (cb >> 1));
      int bo = (row * 128 + cb) ^ ((row & 7) << 4);
      *(int4*)(ldsH + bo) = vh;
      *(int4*)(ldsL + bo) = vl;
    }
    __syncthreads();
#pragma unroll 2
    for (int tp = 0; tp < 8; ++tp) {
      int jr = tp * 16 + (l & 15);               // A row in panel
      int sw = (jr & 7) << 4;
      int rb = jr * 128 + ((l >> 4) << 4);
      bf16x8 ah0 = *(bf16x8*)(ldsH + (rb ^ sw));
      bf16x8 ah1 = *(bf16x8*)(ldsH + ((rb + 64) ^ sw));
      bf16x8 al0 = *(bf16x8*)(ldsL + (rb ^ sw));
      bf16x8 al1 = *(bf16x8*)(ldsL + ((rb + 64) ^ sw));
      int jbase = j0c + p * PJ + tp * 16 + ((l >> 4) << 2);
      // 4 independent 3-deep chains (2 subtiles x 2 K-halves)
      f32x4 aA = {0.f, 0.f, 0.f, 0.f}, aB = {0.f, 0.f, 0.f, 0.f};
      f32x4 aC = {0.f, 0.f, 0.f, 0.f}, aD = {0.f, 0.f, 0.f, 0.f};
      aA = __builtin_amdgcn_mfma_f32_16x16x32_bf16(ah0, bh[0][0], aA, 0, 0, 0);
      aB = __builtin_amdgcn_mfma_f32_16x16x32_bf16(ah1, bh[0][1], aB, 0, 0, 0);
      aC = __builtin_amdgcn_mfma_f32_16x16x32_bf16(ah0, bh[1][0], aC, 0, 0, 0);
      aD = __builtin_amdgcn_mfma_f32_16x16x32_bf16(ah1, bh[1][1], aD, 0, 0, 0);
      aA = __builtin_amdgcn_mfma_f32_16x16x32_bf16(ah0, bl[0][0], aA, 0, 0, 0);
      aB = __builtin_amdgcn_mfma_f32_16x16x32_bf16(ah1, bl[0][1], aB, 0, 0, 0);
      aC = __builtin_amdgcn_mfma_f32_16x16x32_bf16(ah0, bl[1][0], aC, 0, 0, 0);
      aD = __builtin_amdgcn_mfma_f32_16x16x32_bf16(ah1, bl[1][1], aD, 0, 0, 0);
      aA = __builtin_amdgcn_mfma_f32_16x16x32_bf16(al0, bh[0][0], aA, 0, 0, 0);
      aB = __builtin_amdgcn_mfma_f32_16x16x32_bf16(al1, bh[0][1], aB, 0, 0, 0);
      aC = __builtin_amdgcn_mfma_f32_16x16x32_bf16(al0, bh[1][0], aC, 0, 0, 0);
      aD = __builtin_amdgcn_mfma_f32_16x16x32_bf16(al1, bh[1][1], aD, 0, 0, 0);
#pragma unroll
      for (int r = 0; r < 4; ++r) {
        int jj = jbase + r;
        float v0 = (jj < jlim) ? (aA[r] + aB[r]) : NEG_INF;
        INSERT10(v0, jj, vals0, idx0);
        float v1 = (jj < jlim) ? (aC[r] + aD[r]) : NEG_INF;
        INSERT10(v1, jj, vals1, idx1);
      }
    }
  }

  // in-wave merge of the 4 lane-groups' sorted lists (butterfly tournament),
  // then lanes 0..15 store top-10 per (i, chunk)
#pragma unroll
  for (int s = 0; s < 2; ++s) {
    float* V = s ? vals1 : vals0;
    int* I = s ? idx1 : idx0;
    float kv[10]; int kc[10];
#pragma unroll
    for (int t = 0; t < 10; ++t) {
      float v = V[0]; int c = I[0];
      float vo = __shfl_xor(v, 16, 64); int co = __shfl_xor(c, 16, 64);
      if (vo > v || (vo == v && co < c)) { v = vo; c = co; }
      vo = __shfl_xor(v, 32, 64); co = __shfl_xor(c, 32, 64);
      if (vo > v || (vo == v && co < c)) { v = vo; c = co; }
      if (V[0] == v && I[0] == c) {   // this lane owned the winner: pop
#pragma unroll
        for (int m = 0; m < 9; ++m) { V[m] = V[m + 1]; I[m] = I[m + 1]; }
        V[9] = NEG_INF; I[9] = 0x7fffffff;
      }
      kv[t] = v; kc[t] = c;
    }
    int i = ib + s * 16 + (l & 15);
    if (l < 16 && i < N_ITEM) {
      size_t base = ((size_t)i * NJC + blockIdx.y) * 10;
#pragma unroll
      for (int t = 0; t < 10; ++t) { pv[base + t] = kv[t]; pi[base + t] = kc[t]; }
    }
  }
}

// ---------------- merge 160 partial candidates -> top-10 + dis ---------------
__global__ __launch_bounds__(256) void merge_topk(
    const float* __restrict__ pv, const int* __restrict__ pi,
    float* __restrict__ tv, int* __restrict__ tc, float* __restrict__ dis)
{
  int lane = threadIdx.x & 63;
  int row = blockIdx.x * 4 + (threadIdx.x >> 6);
  size_t base = (size_t)row * (NJC * 10);        // 160 = 64 + 64 + 32
  float cv[3]; int ci[3];
  cv[0] = pv[base + lane];        ci[0] = pi[base + lane];
  cv[1] = pv[base + 64 + lane];   ci[1] = pi[base + 64 + lane];
  if (lane < 32) { cv[2] = pv[base + 128 + lane]; ci[2] = pi[base + 128 + lane]; }
  else           { cv[2] = NEG_INF; ci[2] = 0x7fffffff; }
  float deg = 0.f, keepv = 0.f; int keepc = 0;
  for (int t = 0; t < 10; ++t) {
    // local max of 3 with smaller-idx tie-break
    float mv = cv[0]; int mi = ci[0]; int slot = 0;
    if (cv[1] > mv || (cv[1] == mv && ci[1] < mi)) { mv = cv[1]; mi = ci[1]; slot = 1; }
    if (cv[2] > mv || (cv[2] == mv && ci[2] < mi)) { mv = cv[2]; mi = ci[2]; slot = 2; }
    float v = mv; int c = mi;
#pragma unroll
    for (int off = 32; off; off >>= 1) {
      float vo = __shfl_xor(v, off, 64);
      int co = __shfl_xor(c, off, 64);
      if (vo > v || (vo == v && co < c)) { v = vo; c = co; }
    }
    deg += v;
    if (mv == v && mi == c) {   // this lane owned the winner
      if (slot == 0) { cv[0] = NEG_INF; ci[0] = 0x7fffffff; }
      else if (slot == 1) { cv[1] = NEG_INF; ci[1] = 0x7fffffff; }
      else { cv[2] = NEG_INF; ci[2] = 0x7fffffff; }
    }
    if (lane == t) { keepv = v; keepc = c; }
  }
  if (lane < 10) { tv[(size_t)row * 10 + lane] = keepv; tc[(size_t)row * 10 + lane] = keepc; }
  if (lane == 0) dis[row] = deg > 0.f ? rsqrtf(deg) : 0.f;
}

// ---------------- fused SPMM (new + orig neighbors) --------------------------
__global__ __launch_bounds__(256) void fused_spmm(
    const float* __restrict__ tv, const int* __restrict__ tc, const float* __restrict__ dis,
    const float* __restrict__ ow, const int* __restrict__ oc,
    const float* __restrict__ item_emb, float* __restrict__ agg)
{
  int lane = threadIdx.x & 63;
  int row = blockIdx.x * 4 + (threadIdx.x >> 6);
  float disr = dis[row];
  float acc = 0.f;
#pragma unroll
  for (int t = 0; t < 10; ++t) {
    int c = tc[(size_t)row * 10 + t];
    float w = 0.1f * disr * tv[(size_t)row * 10 + t] * dis[c];
    acc += w * item_emb[(size_t)c * 64 + lane];
  }
#pragma unroll
  for (int t = 0; t < 10; ++t) {
    int c = oc[(size_t)row * 10 + t];
    float w = 0.9f * ow[(size_t)row * 10 + t];
    acc += w * item_emb[(size_t)c * 64 + lane];
  }
  agg[(size_t)row * 64 + lane] = acc;
}

// ---------------- attention combine + h_norm ---------------------------------
__global__ __launch_bounds__(256) void attn_h(
    const float* __restrict__ ai, const float* __restrict__ at,
    const float* __restrict__ Wq1, const float* __restrict__ bq1,
    const float* __restrict__ wq2, float* __restrict__ hn)
{
  int lane = threadIdx.x & 63;
  int row = blockIdx.x * 4 + (threadIdx.x >> 6);
  const float* xi = ai + (size_t)row * 64;
  const float* xt = at + (size_t)row * 64;
  float y0 = bq1[lane], y1 = bq1[lane];
  for (int k = 0; k < 64; ++k) {
    float w = Wq1[k * 64 + lane];
    y0 += xi[k] * w;
    y1 += xt[k] * w;
  }
  float wq = wq2[lane];
  float s0 = wred_sum(tanhf(y0) * wq);
  float s1 = wred_sum(tanhf(y1) * wq);
  float m = fmaxf(s0, s1);
  float e0 = expf(s0 - m), e1 = expf(s1 - m);
  float inv = 1.f / (e0 + e1);
  float h = (e0 * inv) * xi[lane] + (e1 * inv) * xt[lane];
  float n2 = wred_sum(h * h);
  float nrm = fmaxf(sqrtf(n2), 1e-12f);
  hn[(size_t)row * 64 + lane] = h / nrm;
}

// ---------------- UI graph helpers -------------------------------------------
__global__ void ui_zero(int* degi, int* cursor)
{
  int n = blockIdx.x * 256 + threadIdx.x;
  if (n < N_NODE) { degi[n] = 0; cursor[n] = 0; }
}

__global__ void ui_count(const int* __restrict__ r, int* degi)
{
  int e = blockIdx.x * 256 + threadIdx.x;
  if (e < N_EDGE) atomicAdd(&degi[r[e]], 1);
}

__global__ __launch_bounds__(1024) void ui_scan(const int* __restrict__ degi, int* __restrict__ offs)
{
  __shared__ int sums[1024];
  int tid = threadIdx.x;
  int base_i = tid * 32;
  int s = 0;
  for (int k = 0; k < 32; ++k) { int idx = base_i + k; s += (idx < N_NODE) ? degi[idx] : 0; }
  sums[tid] = s;
  __syncthreads();
  for (int off = 1; off < 1024; off <<= 1) {
    int v = (tid >= off) ? sums[tid - off] : 0;
    __syncthreads();
    sums[tid] += v;
    __syncthreads();
  }
  int run = (tid == 0) ? 0 : sums[tid - 1];
  for (int k = 0; k < 32; ++k) {
    int idx = base_i + k;
    if (idx < N_NODE) { offs[idx] = run; run += degi[idx]; }
  }
  if (tid == 1023) offs[N_NODE] = run;
}

__global__ void ui_dis(const int* __restrict__ degi, float* __restrict__ dis)
{
  int n = blockIdx.x * 256 + threadIdx.x;
  if (n < N_NODE) dis[n] = degi[n] > 0 ? rsqrtf((float)degi[n]) : 0.f;
}

__global__ void ui_fill(const int* __restrict__ r, const int* __restrict__ c,
                        const int* __restrict__ offs, int* cursor, int* __restrict__ csr)
{
  int e = blockIdx.x * 256 + threadIdx.x;
  if (e < N_EDGE) {
    int rr = r[e];
    int pos = offs[rr] + atomicAdd(&cursor[rr], 1);
    csr[pos] = c[e];
  }
}

template <bool FIRST>
__global__ __launch_bounds__(256) void ui_prop(
    const float* __restrict__ in, const float* __restrict__ ue, const float* __restrict__ ie,
    float* __restrict__ out, const int* __restrict__ offs, const int* __restrict__ csr,
    const float* __restrict__ dis)
{
  int lane = threadIdx.x & 63;
  int row = blockIdx.x * 4 + (threadIdx.x >> 6);
  float acc = 0.f;
  int e0 = offs[row], e1 = offs[row + 1];
  for (int e = e0; e < e1; ++e) {
    int cc = csr[e];
    const float* src = FIRST
        ? (cc < N_USER ? ue + (size_t)cc * 64 : ie + (size_t)(cc - N_USER) * 64)
        : in + (size_t)cc * 64;
    acc += dis[cc] * src[lane];
  }
  out[(size_t)row * 64 + lane] = dis[row] * acc;
}

__global__ void ui_final(const float* __restrict__ ue, const float* __restrict__ ie,
                         const float* __restrict__ E1, const float* __restrict__ E2,
                         const float* __restrict__ hn, float* __restrict__ out)
{
  int idx = blockIdx.x * 256 + threadIdx.x;   // 0 .. 2047999
  int n = idx >> 6, d = idx & 63;
  float e0 = (n < N_USER) ? ue[idx] : ie[(size_t)(n - N_USER) * 64 + d];
  float v = (e0 + E1[idx] + E2[idx]) * (1.f / 3.f);
  if (n >= N_USER) v += hn[(size_t)(n - N_USER) * 64 + d];
  out[idx] = v;
}

// ---------------- host driver ------------------------------------------------
extern "C" void kernel_launch(void* const* d_in, const int* in_sizes, int n_in,
                              void* d_out, int out_size, void* d_ws, size_t ws_size,
                              hipStream_t stream)
{
  (void)in_sizes; (void)n_in; (void)out_size; (void)ws_size;
  const float* user_emb = (const float*)d_in[0];
  const float* item_emb = (const float*)d_in[1];
  const float* v_feat   = (const float*)d_in[2];
  const float* t_feat   = (const float*)d_in[3];
  const float* W_v      = (const float*)d_in[4];
  const float* b_v      = (const float*)d_in[5];
  const float* W_t      = (const float*)d_in[6];
  const float* b_t      = (const float*)d_in[7];
  const float* Wq1      = (const float*)d_in[8];
  const float* bq1      = (const float*)d_in[9];
  const float* wq2      = (const float*)d_in[10];
  const float* ow_i     = (const float*)d_in[11];
  const float* ow_t     = (const float*)d_in[12];
  const int*   eidx     = (const int*)d_in[13];
  const int*   oc_i     = (const int*)d_in[14];
  const int*   oc_t     = (const int*)d_in[15];
  float* out = (float*)d_out;

  char* wp = (char*)d_ws;
  auto alloc = [&](size_t bytes) -> void* {
    void* p = (void*)wp;
    wp += (bytes + 255) & ~(size_t)255;
    return p;
  };
  // two big buffers: partial-topk first, then aliased as ego layer buffers
  float* BIG0 = (float*)alloc((size_t)N_NODE * 64 * 4 + 1024);   // >= 8.192 MB
  float* BIG1 = (float*)alloc((size_t)N_NODE * 64 * 4 + 1024);
  float* pv = BIG0;              // needs 8000*160*4 = 5.12 MB
  int*   pi = (int*)BIG1;
  float* E1 = BIG0;
  float* E2 = BIG1;

  float*          Pp  = (float*)alloc((size_t)2 * N_ITEM * 64 * 4);  // 2 k-chunk partials
  unsigned short* Xh  = (unsigned short*)alloc((size_t)N_ITEM * 64 * 2);
  unsigned short* Xl  = (unsigned short*)alloc((size_t)N_ITEM * 64 * 2);
  float* tv_i  = (float*)alloc((size_t)N_ITEM * 10 * 4);
  int*   tc_i  = (int*)  alloc((size_t)N_ITEM * 10 * 4);
  float* dis_i = (float*)alloc((size_t)N_ITEM * 4);
  float* tv_t  = (float*)alloc((size_t)N_ITEM * 10 * 4);
  int*   tc_t  = (int*)  alloc((size_t)N_ITEM * 10 * 4);
  float* dis_t = (float*)alloc((size_t)N_ITEM * 4);
  float* agg_i = (float*)alloc((size_t)N_ITEM * 64 * 4);
  float* agg_t = (float*)alloc((size_t)N_ITEM * 64 * 4);
  float* hn    = (float*)alloc((size_t)N_ITEM * 64 * 4);
  int*   degi  = (int*)  alloc((size_t)N_NODE * 4);
  int*   curs  = (int*)  alloc((size_t)N_NODE * 4);
  int*   offs  = (int*)  alloc((size_t)(N_NODE + 1) * 4);
  float* disui = (float*)alloc((size_t)N_NODE * 4);
  int*   csr   = (int*)  alloc((size_t)N_EDGE * 4);

  // ---- image modality ----
  gemm64<<<dim3(125, 2), 256, 0, stream>>>(v_feat, W_v, Pp, 2048, 1024);
  norm_split<<<2000, 256, 0, stream>>>(Pp, b_v, Xh, Xl);
  sim_topk_mfma<<<dim3(63, NJC), 256, 0, stream>>>(Xh, Xl, pv, pi);
  merge_topk<<<2000, 256, 0, stream>>>(pv, pi, tv_i, tc_i, dis_i);
  // ---- text modality ----
  gemm64<<<dim3(125, 2), 256, 0, stream>>>(t_feat, W_t, Pp, 384, 192);
  norm_split<<<2000, 256, 0, stream>>>(Pp, b_t, Xh, Xl);
  sim_topk_mfma<<<dim3(63, NJC), 256, 0, stream>>>(Xh, Xl, pv, pi);
  merge_topk<<<2000, 256, 0, stream>>>(pv, pi, tv_t, tc_t, dis_t);
  // ---- fused SPMM + attention ----
  fused_spmm<<<2000, 256, 0, stream>>>(tv_i, tc_i, dis_i, ow_i, oc_i, item_emb, agg_i);
  fused_spmm<<<2000, 256, 0, stream>>>(tv_t, tc_t, dis_t, ow_t, oc_t, item_emb, agg_t);
  attn_h<<<2000, 256, 0, stream>>>(agg_i, agg_t, Wq1, bq1, wq2, hn);
  // ---- user-item graph ----
  ui_zero<<<125, 256, 0, stream>>>(degi, curs);
  ui_count<<<N_EDGE / 256, 256, 0, stream>>>(eidx, degi);
  ui_scan<<<1, 1024, 0, stream>>>(degi, offs);
  ui_dis<<<125, 256, 0, stream>>>(degi, disui);
  ui_fill<<<N_EDGE / 256, 256, 0, stream>>>(eidx, eidx + N_EDGE, offs, curs, csr);
  ui_prop<true><<<8000, 256, 0, stream>>>(nullptr, user_emb, item_emb, E1, offs, csr, disui);
  ui_prop<false><<<8000, 256, 0, stream>>>(E1, user_emb, item_emb, E2, offs, csr, disui);
  ui_final<<<8000, 256, 0, stream>>>(user_emb, item_emb, E1, E2, hn, out);
}

// Round 4
// 633.394 us; speedup vs baseline: 2.2327x; 1.1025x over previous
//
#include <hip/hip_runtime.h>
#include <math.h>

#define N_USER 24000
#define N_ITEM 8000
#define N_NODE 32000
#define N_EDGE 800000
#define NJC    10          // j-chunks for sim/topk
#define JCH    800         // j per chunk = 50 tiles of 16 = 25 panels of 32
#define NEG_INF -1e30f

typedef __attribute__((ext_vector_type(8))) short bf16x8;
typedef __attribute__((ext_vector_type(4))) float f32x4;

__device__ __forceinline__ float wred_sum(float v) {
#pragma unroll
  for (int off = 32; off; off >>= 1) v += __shfl_xor(v, off, 64);
  return v;
}

__device__ __forceinline__ unsigned short f2bf(float f) {
  unsigned int u = __float_as_uint(f);
  unsigned int r = (u + 0x7fffu + ((u >> 16) & 1u)) >> 16;
  return (unsigned short)r;
}
__device__ __forceinline__ float bf2f(unsigned short h) {
  return __uint_as_float(((unsigned int)h) << 16);
}

#define INSERT10(vv, jj, V, I)                          \
  if ((vv) > V[9]) {                                    \
    float cv_ = (vv); int ci_ = (jj);                   \
    _Pragma("unroll")                                   \
    for (int s_ = 0; s_ < 10; ++s_) {                   \
      if (cv_ > V[s_]) {                                \
        float tv_ = V[s_]; int ti_ = I[s_];             \
        V[s_] = cv_; I[s_] = ci_; cv_ = tv_; ci_ = ti_; \
      }                                                 \
    }                                                   \
  }

// argmax over 8 values (pairwise tree, ties keep smaller q)
__device__ __forceinline__ void tree8(const float* v, float& m, int& qm) {
  float m0 = v[0] >= v[1] ? v[0] : v[1]; int q0 = v[0] >= v[1] ? 0 : 1;
  float m1 = v[2] >= v[3] ? v[2] : v[3]; int q1 = v[2] >= v[3] ? 2 : 3;
  float m2 = v[4] >= v[5] ? v[4] : v[5]; int q2 = v[4] >= v[5] ? 4 : 5;
  float m3 = v[6] >= v[7] ? v[6] : v[7]; int q3 = v[6] >= v[7] ? 6 : 7;
  float n0 = m0 >= m1 ? m0 : m1; int p0 = m0 >= m1 ? q0 : q1;
  float n1 = m2 >= m3 ? m2 : m3; int p1 = m2 >= m3 ? q2 : q3;
  m = n0 >= n1 ? n0 : n1; qm = n0 >= n1 ? p0 : p1;
}

// ---------------- projection GEMM partial: P[chunk] = X[:, kc] @ W[kc, :] ----
__global__ __launch_bounds__(256) void gemm64(
    const float* __restrict__ X, const float* __restrict__ W,
    float* __restrict__ P, int K, int Klen)
{
  __shared__ float As[32 * 64];   // As[k][r]
  __shared__ float Bs[32 * 64];   // Bs[k][n]
  const int tid = threadIdx.x;
  const int m0 = blockIdx.x * 64;
  const int kc0 = blockIdx.y * Klen;
  float* out = P + (size_t)blockIdx.y * N_ITEM * 64;
  const int tr = tid >> 4, tc = tid & 15;
  float acc[4][4] = {};
  for (int k0 = kc0; k0 < kc0 + Klen; k0 += 32) {
    __syncthreads();
#pragma unroll
    for (int l = 0; l < 2; ++l) {
      int f4 = tid + l * 256;
      int r = f4 >> 3, kq = f4 & 7;        // A: 64 rows x 8 float4
      float4 a = *(const float4*)(X + (size_t)(m0 + r) * K + k0 + kq * 4);
      As[(kq * 4 + 0) * 64 + r] = a.x;
      As[(kq * 4 + 1) * 64 + r] = a.y;
      As[(kq * 4 + 2) * 64 + r] = a.z;
      As[(kq * 4 + 3) * 64 + r] = a.w;
      int kb = f4 >> 4, nq = f4 & 15;      // B: 32 rows x 16 float4
      *(float4*)(Bs + kb * 64 + nq * 4) =
          *(const float4*)(W + (size_t)(k0 + kb) * 64 + nq * 4);
    }
    __syncthreads();
#pragma unroll
    for (int k = 0; k < 32; ++k) {
      float4 a4 = *(const float4*)(As + k * 64 + tr * 4);
      float4 b4 = *(const float4*)(Bs + k * 64 + tc * 4);
      float av[4] = {a4.x, a4.y, a4.z, a4.w};
      float bv[4] = {b4.x, b4.y, b4.z, b4.w};
#pragma unroll
      for (int ri = 0; ri < 4; ++ri)
#pragma unroll
        for (int ci = 0; ci < 4; ++ci) acc[ri][ci] += av[ri] * bv[ci];
    }
  }
#pragma unroll
  for (int ri = 0; ri < 4; ++ri) {
    float4 o;
    o.x = acc[ri][0]; o.y = acc[ri][1]; o.z = acc[ri][2]; o.w = acc[ri][3];
    *(float4*)(out + (size_t)(m0 + tr * 4 + ri) * 64 + tc * 4) = o;
  }
}

// ---------------- sum nk partials + bias, L2-normalize, split bf16 hi/lo -----
__global__ __launch_bounds__(256) void norm_split(
    const float* __restrict__ P, const float* __restrict__ bias,
    unsigned short* __restrict__ Xh, unsigned short* __restrict__ Xl, int nk)
{
  int row = blockIdx.x * 4 + (threadIdx.x >> 6);
  int lane = threadIdx.x & 63;
  size_t o = (size_t)row * 64 + lane;
  float v = bias[lane];
  for (int q = 0; q < nk; ++q) v += P[(size_t)q * N_ITEM * 64 + o];
  float ss = wred_sum(v * v);
  float xn = v * rsqrtf(ss);
  unsigned short hi = f2bf(xn);
  Xh[o] = hi;
  Xl[o] = f2bf(xn - bf2f(hi));
}

// ---------------- MFMA sim + argmax-batched per-lane top-10 ------------------
// grid (125, NJC), block 128 (2 waves). Wave: 32 i (2x16 subtiles).
// A = j-rows (LDS dbuf panel of 32 rows), B = i-rows -> C[j_loc, i_loc].
__global__ __launch_bounds__(128) void sim_topk_mfma(
    const unsigned short* __restrict__ Xh, const unsigned short* __restrict__ Xl,
    float* __restrict__ pv, int* __restrict__ pi)
{
  __shared__ char lds[2 * 2 * 32 * 128];   // 16 KiB: [buf][hi/lo][32 rows][128B]
  const int tid = threadIdx.x;
  const int l = tid & 63;
  const int wid = tid >> 6;
  const int ib = blockIdx.x * 64 + wid * 32;
  const int jc = blockIdx.y * JCH;
  const int g4 = (l >> 4) << 2;            // C-row group offset

  // B-fragments (i side), loaded once. s = i-subtile, kh = K-half.
  bf16x8 bh[2][2], bl[2][2];
#pragma unroll
  for (int s = 0; s < 2; ++s) {
    int irow = ib + s * 16 + (l & 15);
    int ksl = (l >> 4) * 8;
#pragma unroll
    for (int kh = 0; kh < 2; ++kh) {
      bh[s][kh] = *(const bf16x8*)(Xh + (size_t)irow * 64 + kh * 32 + ksl);
      bl[s][kh] = *(const bf16x8*)(Xl + (size_t)irow * 64 + kh * 32 + ksl);
    }
  }

  float V0[10], V1[10]; int I0[10], I1[10];
#pragma unroll
  for (int t = 0; t < 10; ++t) {
    V0[t] = NEG_INF; I0[t] = -1; V1[t] = NEG_INF; I1[t] = -1;
  }

  auto stage = [&](int b, int p) {
#pragma unroll
    for (int s2 = 0; s2 < 2; ++s2) {
      int u = tid + s2 * 128;              // 256 16B-units per matrix
      int row = u >> 3, cb = (u & 7) * 16;
      int gr = jc + p * 32 + row;
      int4 vh = *(const int4*)(Xh + (size_t)gr * 64 + (cb >> 1));
      int4 vl = *(const int4*)(Xl + (size_t)gr * 64 + (cb >> 1));
      int bo = (row * 128 + cb) ^ ((row & 7) << 4);
      *(int4*)(lds + b * 8192 + bo) = vh;
      *(int4*)(lds + b * 8192 + 4096 + bo) = vl;
    }
  };

  stage(0, 0);
  int cur = 0;
  for (int p = 0; p < 25; ++p) {           // 25 panels x 2 j-tiles
    __syncthreads();
    if (p < 24) stage(cur ^ 1, p + 1);
    const char* ldsH = lds + cur * 8192;
    const char* ldsL = ldsH + 4096;
    f32x4 acc[2][2] = {};
#pragma unroll
    for (int t = 0; t < 2; ++t) {
      int jr = t * 16 + (l & 15);
      int sw = (jr & 7) << 4;
      int rb = jr * 128 + ((l >> 4) << 4);
      bf16x8 ah0 = *(const bf16x8*)(ldsH + (rb ^ sw));
      bf16x8 ah1 = *(const bf16x8*)(ldsH + ((rb + 64) ^ sw));
      bf16x8 al0 = *(const bf16x8*)(ldsL + (rb ^ sw));
      bf16x8 al1 = *(const bf16x8*)(ldsL + ((rb + 64) ^ sw));
#pragma unroll
      for (int s = 0; s < 2; ++s) {
        acc[t][s] = __builtin_amdgcn_mfma_f32_16x16x32_bf16(ah0, bh[s][0], acc[t][s], 0, 0, 0);
        acc[t][s] = __builtin_amdgcn_mfma_f32_16x16x32_bf16(ah1, bh[s][1], acc[t][s], 0, 0, 0);
        acc[t][s] = __builtin_amdgcn_mfma_f32_16x16x32_bf16(ah0, bl[s][0], acc[t][s], 0, 0, 0);
        acc[t][s] = __builtin_amdgcn_mfma_f32_16x16x32_bf16(ah1, bl[s][1], acc[t][s], 0, 0, 0);
        acc[t][s] = __builtin_amdgcn_mfma_f32_16x16x32_bf16(al0, bh[s][0], acc[t][s], 0, 0, 0);
        acc[t][s] = __builtin_amdgcn_mfma_f32_16x16x32_bf16(al1, bh[s][1], acc[t][s], 0, 0, 0);
      }
    }
    // epilogue: per list, argmax insert + rare brute fallback
    const int jb = jc + p * 32 + g4;       // + tq*16 + (q&3)
#pragma unroll
    for (int s = 0; s < 2; ++s) {
      float* V = s ? V1 : V0;
      int* I = s ? I1 : I0;
      float v[8];
#pragma unroll
      for (int q = 0; q < 8; ++q) v[q] = acc[q >> 2][s][q & 3];
      float m; int qm;
      tree8(v, m, qm);
      if (__any(m > V[9])) {
        int jm = jb + ((qm >> 2) << 4) + (qm & 3);
        INSERT10(m, jm, V, I);
#pragma unroll
        for (int q = 0; q < 8; ++q) v[q] = (q == qm) ? NEG_INF : v[q];
        float m2; int q2;
        tree8(v, m2, q2);
        if (__any(m2 > V[9])) {
#pragma unroll
          for (int q = 0; q < 8; ++q) {
            int jq = jb + ((q >> 2) << 4) + (q & 3);
            INSERT10(v[q], jq, V, I);
          }
        }
      }
    }
    cur ^= 1;
  }

  // in-wave merge of 4 lane-groups (shfl 16/32 tournament), lanes 0..15 store
#pragma unroll
  for (int s = 0; s < 2; ++s) {
    float* V = s ? V1 : V0;
    int* I = s ? I1 : I0;
    float kv[10]; int kc[10];
#pragma unroll
    for (int t = 0; t < 10; ++t) {
      float v = V[0]; int c = I[0];
      float vo = __shfl_xor(v, 16, 64); int co = __shfl_xor(c, 16, 64);
      if (vo > v || (vo == v && co < c)) { v = vo; c = co; }
      vo = __shfl_xor(v, 32, 64); co = __shfl_xor(c, 32, 64);
      if (vo > v || (vo == v && co < c)) { v = vo; c = co; }
      if (V[0] == v && I[0] == c) {        // owner pops
#pragma unroll
        for (int m = 0; m < 9; ++m) { V[m] = V[m + 1]; I[m] = I[m + 1]; }
        V[9] = NEG_INF; I[9] = 0x7fffffff;
      }
      kv[t] = v; kc[t] = c;
    }
    int i = ib + s * 16 + (l & 15);
    if (l < 16) {
      size_t base = ((size_t)i * NJC + blockIdx.y) * 10;
#pragma unroll
      for (int t = 0; t < 10; ++t) { pv[base + t] = kv[t]; pi[base + t] = kc[t]; }
    }
  }
}

// ---------------- merge 100 partial candidates -> top-10 + dis ---------------
__global__ __launch_bounds__(256) void merge_topk(
    const float* __restrict__ pv, const int* __restrict__ pi,
    float* __restrict__ tv, int* __restrict__ tc, float* __restrict__ dis)
{
  int lane = threadIdx.x & 63;
  int row = blockIdx.x * 4 + (threadIdx.x >> 6);
  size_t base = (size_t)row * (NJC * 10);  // 100 = 64 + 36
  float cv[2]; int ci[2];
  cv[0] = pv[base + lane];        ci[0] = pi[base + lane];
  if (lane < 36) { cv[1] = pv[base + 64 + lane]; ci[1] = pi[base + 64 + lane]; }
  else           { cv[1] = NEG_INF; ci[1] = 0x7fffffff; }
  float deg = 0.f, keepv = 0.f; int keepc = 0;
  for (int t = 0; t < 10; ++t) {
    float mv = cv[0]; int mi = ci[0]; int slot = 0;
    if (cv[1] > mv || (cv[1] == mv && ci[1] < mi)) { mv = cv[1]; mi = ci[1]; slot = 1; }
    float v = mv; int c = mi;
#pragma unroll
    for (int off = 32; off; off >>= 1) {
      float vo = __shfl_xor(v, off, 64);
      int co = __shfl_xor(c, off, 64);
      if (vo > v || (vo == v && co < c)) { v = vo; c = co; }
    }
    deg += v;
    if (mv == v && mi == c) {
      if (slot == 0) { cv[0] = NEG_INF; ci[0] = 0x7fffffff; }
      else           { cv[1] = NEG_INF; ci[1] = 0x7fffffff; }
    }
    if (lane == t) { keepv = v; keepc = c; }
  }
  if (lane < 10) { tv[(size_t)row * 10 + lane] = keepv; tc[(size_t)row * 10 + lane] = keepc; }
  if (lane == 0) dis[row] = deg > 0.f ? rsqrtf(deg) : 0.f;
}

// ---------------- fused SPMM (both modalities) + attention + h_norm ----------
__global__ __launch_bounds__(256) void spmm_attn(
    const float* __restrict__ tv_i, const int* __restrict__ tc_i, const float* __restrict__ dis_i,
    const float* __restrict__ ow_i, const int* __restrict__ oc_i,
    const float* __restrict__ tv_t, const int* __restrict__ tc_t, const float* __restrict__ dis_t,
    const float* __restrict__ ow_t, const int* __restrict__ oc_t,
    const float* __restrict__ item_emb,
    const float* __restrict__ Wq1, const float* __restrict__ bq1,
    const float* __restrict__ wq2, float* __restrict__ hn)
{
  __shared__ float Wlds[64 * 64];
  __shared__ float sm[4][2][64];
  int tid = threadIdx.x;
  int lane = tid & 63, wid = tid >> 6;
  int row = blockIdx.x * 4 + wid;
#pragma unroll
  for (int s = 0; s < 4; ++s) {
    int idx = tid + s * 256;
    ((float4*)Wlds)[idx] = ((const float4*)Wq1)[idx];
  }
  float a0 = 0.f, a1 = 0.f;
  {
    float disr = dis_i[row];
#pragma unroll
    for (int t = 0; t < 10; ++t) {
      int c = tc_i[(size_t)row * 10 + t];
      a0 += 0.1f * disr * tv_i[(size_t)row * 10 + t] * dis_i[c] * item_emb[(size_t)c * 64 + lane];
    }
#pragma unroll
    for (int t = 0; t < 10; ++t) {
      int c = oc_i[(size_t)row * 10 + t];
      a0 += 0.9f * ow_i[(size_t)row * 10 + t] * item_emb[(size_t)c * 64 + lane];
    }
  }
  {
    float disr = dis_t[row];
#pragma unroll
    for (int t = 0; t < 10; ++t) {
      int c = tc_t[(size_t)row * 10 + t];
      a1 += 0.1f * disr * tv_t[(size_t)row * 10 + t] * dis_t[c] * item_emb[(size_t)c * 64 + lane];
    }
#pragma unroll
    for (int t = 0; t < 10; ++t) {
      int c = oc_t[(size_t)row * 10 + t];
      a1 += 0.9f * ow_t[(size_t)row * 10 + t] * item_emb[(size_t)c * 64 + lane];
    }
  }
  sm[wid][0][lane] = a0;
  sm[wid][1][lane] = a1;
  __syncthreads();
  float y0 = bq1[lane], y1 = bq1[lane];
  for (int k = 0; k < 64; ++k) {
    float w = Wlds[k * 64 + lane];
    y0 += sm[wid][0][k] * w;
    y1 += sm[wid][1][k] * w;
  }
  float wq = wq2[lane];
  float s0 = wred_sum(tanhf(y0) * wq);
  float s1 = wred_sum(tanhf(y1) * wq);
  float mx = fmaxf(s0, s1);
  float e0 = expf(s0 - mx), e1 = expf(s1 - mx);
  float inv = 1.f / (e0 + e1);
  float h = (e0 * inv) * a0 + (e1 * inv) * a1;
  float n2 = wred_sum(h * h);
  float nrm = fmaxf(sqrtf(n2), 1e-12f);
  hn[(size_t)row * 64 + lane] = h / nrm;
}

// ---------------- UI graph helpers -------------------------------------------
__global__ void ui_zero(int* degi, int* cursor)
{
  int n = blockIdx.x * 256 + threadIdx.x;
  if (n < N_NODE) { degi[n] = 0; cursor[n] = 0; }
}

__global__ void ui_count(const int* __restrict__ r, int* degi)
{
  int e = blockIdx.x * 256 + threadIdx.x;
  if (e < N_EDGE) atomicAdd(&degi[r[e]], 1);
}

// coalesced 3-kernel scan
__global__ __launch_bounds__(256) void ui_blocksum(const int* __restrict__ degi, int* __restrict__ bsum)
{
  __shared__ int ws4[4];
  int tid = threadIdx.x;
  int v = degi[blockIdx.x * 256 + tid];
#pragma unroll
  for (int off = 32; off; off >>= 1) v += __shfl_xor(v, off, 64);
  if ((tid & 63) == 0) ws4[tid >> 6] = v;
  __syncthreads();
  if (tid == 0) bsum[blockIdx.x] = ws4[0] + ws4[1] + ws4[2] + ws4[3];
}

__global__ __launch_bounds__(128) void ui_scanb(const int* __restrict__ bsum, int* __restrict__ bbase, int* __restrict__ offs)
{
  __shared__ int s[128];
  int t = threadIdx.x;
  int v = (t < 125) ? bsum[t] : 0;
  s[t] = v;
  __syncthreads();
  for (int off = 1; off < 128; off <<= 1) {
    int tmp = (t >= off) ? s[t - off] : 0;
    __syncthreads();
    s[t] += tmp;
    __syncthreads();
  }
  if (t < 125) bbase[t] = s[t] - v;
  if (t == 127) offs[N_NODE] = s[127];
}

__global__ __launch_bounds__(256) void ui_scanc(const int* __restrict__ degi, const int* __restrict__ bbase,
                                                int* __restrict__ offs, float* __restrict__ disui)
{
  __shared__ int wt[4];
  int tid = threadIdx.x;
  int i = blockIdx.x * 256 + tid;
  int d = degi[i];
  int v = d;
#pragma unroll
  for (int off = 1; off < 64; off <<= 1) {
    int n = __shfl_up(v, off, 64);
    if ((tid & 63) >= off) v += n;
  }
  if ((tid & 63) == 63) wt[tid >> 6] = v;
  __syncthreads();
  int add = bbase[blockIdx.x];
  for (int w = 0; w < (tid >> 6); ++w) add += wt[w];
  offs[i] = add + v - d;
  disui[i] = d > 0 ? rsqrtf((float)d) : 0.f;
}

__global__ void ui_fill(const int* __restrict__ r, const int* __restrict__ c,
                        const int* __restrict__ offs, int* cursor, int* __restrict__ csr)
{
  int e = blockIdx.x * 256 + threadIdx.x;
  if (e < N_EDGE) {
    int rr = r[e];
    int pos = offs[rr] + atomicAdd(&cursor[rr], 1);
    csr[pos] = c[e];
  }
}

template <bool FIRST>
__global__ __launch_bounds__(256) void ui_prop(
    const float* __restrict__ in, const float* __restrict__ ue, const float* __restrict__ ie,
    float* __restrict__ out, const int* __restrict__ offs, const int* __restrict__ csr,
    const float* __restrict__ dis)
{
  int lane = threadIdx.x & 63;
  int row = blockIdx.x * 4 + (threadIdx.x >> 6);
  float acc = 0.f;
  int e0 = offs[row], e1 = offs[row + 1];
  for (int e = e0; e < e1; ++e) {
    int cc = csr[e];
    const float* src = FIRST
        ? (cc < N_USER ? ue + (size_t)cc * 64 : ie + (size_t)(cc - N_USER) * 64)
        : in + (size_t)cc * 64;
    acc += dis[cc] * src[lane];
  }
  out[(size_t)row * 64 + lane] = dis[row] * acc;
}

__global__ void ui_final(const float* __restrict__ ue, const float* __restrict__ ie,
                         const float* __restrict__ E1, const float* __restrict__ E2,
                         const float* __restrict__ hn, float* __restrict__ out)
{
  int idx = blockIdx.x * 256 + threadIdx.x;
  int n = idx >> 6, d = idx & 63;
  float e0 = (n < N_USER) ? ue[idx] : ie[(size_t)(n - N_USER) * 64 + d];
  float v = (e0 + E1[idx] + E2[idx]) * (1.f / 3.f);
  if (n >= N_USER) v += hn[(size_t)(n - N_USER) * 64 + d];
  out[idx] = v;
}

// ---------------- host driver ------------------------------------------------
extern "C" void kernel_launch(void* const* d_in, const int* in_sizes, int n_in,
                              void* d_out, int out_size, void* d_ws, size_t ws_size,
                              hipStream_t stream)
{
  (void)in_sizes; (void)n_in; (void)out_size; (void)ws_size;
  const float* user_emb = (const float*)d_in[0];
  const float* item_emb = (const float*)d_in[1];
  const float* v_feat   = (const float*)d_in[2];
  const float* t_feat   = (const float*)d_in[3];
  const float* W_v      = (const float*)d_in[4];
  const float* b_v      = (const float*)d_in[5];
  const float* W_t      = (const float*)d_in[6];
  const float* b_t      = (const float*)d_in[7];
  const float* Wq1      = (const float*)d_in[8];
  const float* bq1      = (const float*)d_in[9];
  const float* wq2      = (const float*)d_in[10];
  const float* ow_i     = (const float*)d_in[11];
  const float* ow_t     = (const float*)d_in[12];
  const int*   eidx     = (const int*)d_in[13];
  const int*   oc_i     = (const int*)d_in[14];
  const int*   oc_t     = (const int*)d_in[15];
  float* out = (float*)d_out;

  char* wp = (char*)d_ws;
  auto alloc = [&](size_t bytes) -> void* {
    void* p = (void*)wp;
    wp += (bytes + 255) & ~(size_t)255;
    return p;
  };
  // big buffers: partial-topk first, then aliased as ego layer buffers
  float* BIG0 = (float*)alloc((size_t)N_NODE * 64 * 4 + 1024);
  float* BIG1 = (float*)alloc((size_t)N_NODE * 64 * 4 + 1024);
  float* pv = BIG0;              // needs 8000*100*4 = 3.2 MB
  int*   pi = (int*)BIG1;
  float* E1 = BIG0;
  float* E2 = BIG1;

  float*          Pp  = (float*)alloc((size_t)4 * N_ITEM * 64 * 4);  // 4 k-chunk partials
  unsigned short* Xh  = (unsigned short*)alloc((size_t)N_ITEM * 64 * 2);
  unsigned short* Xl  = (unsigned short*)alloc((size_t)N_ITEM * 64 * 2);
  float* tv_i  = (float*)alloc((size_t)N_ITEM * 10 * 4);
  int*   tc_i  = (int*)  alloc((size_t)N_ITEM * 10 * 4);
  float* dis_i = (float*)alloc((size_t)N_ITEM * 4);
  float* tv_t  = (float*)alloc((size_t)N_ITEM * 10 * 4);
  int*   tc_t  = (int*)  alloc((size_t)N_ITEM * 10 * 4);
  float* dis_t = (float*)alloc((size_t)N_ITEM * 4);
  float* hn    = (float*)alloc((size_t)N_ITEM * 64 * 4);
  int*   degi  = (int*)  alloc((size_t)N_NODE * 4);
  int*   curs  = (int*)  alloc((size_t)N_NODE * 4);
  int*   offs  = (int*)  alloc((size_t)(N_NODE + 1) * 4);
  float* disui = (float*)alloc((size_t)N_NODE * 4);
  int*   csr   = (int*)  alloc((size_t)N_EDGE * 4);
  int*   bsum  = (int*)  alloc((size_t)128 * 4);
  int*   bbase = (int*)  alloc((size_t)128 * 4);

  // ---- image modality ----
  gemm64<<<dim3(125, 4), 256, 0, stream>>>(v_feat, W_v, Pp, 2048, 512);
  norm_split<<<2000, 256, 0, stream>>>(Pp, b_v, Xh, Xl, 4);
  sim_topk_mfma<<<dim3(125, NJC), 128, 0, stream>>>(Xh, Xl, pv, pi);
  merge_topk<<<2000, 256, 0, stream>>>(pv, pi, tv_i, tc_i, dis_i);
  // ---- text modality ----
  gemm64<<<dim3(125, 2), 256, 0, stream>>>(t_feat, W_t, Pp, 384, 192);
  norm_split<<<2000, 256, 0, stream>>>(Pp, b_t, Xh, Xl, 2);
  sim_topk_mfma<<<dim3(125, NJC), 128, 0, stream>>>(Xh, Xl, pv, pi);
  merge_topk<<<2000, 256, 0, stream>>>(pv, pi, tv_t, tc_t, dis_t);
  // ---- fused SPMM + attention + h_norm ----
  spmm_attn<<<2000, 256, 0, stream>>>(tv_i, tc_i, dis_i, ow_i, oc_i,
                                      tv_t, tc_t, dis_t, ow_t, oc_t,
                                      item_emb, Wq1, bq1, wq2, hn);
  // ---- user-item graph ----
  ui_zero<<<125, 256, 0, stream>>>(degi, curs);
  ui_count<<<N_EDGE / 256, 256, 0, stream>>>(eidx, degi);
  ui_blocksum<<<125, 256, 0, stream>>>(degi, bsum);
  ui_scanb<<<1, 128, 0, stream>>>(bsum, bbase, offs);
  ui_scanc<<<125, 256, 0, stream>>>(degi, bbase, offs, disui);
  ui_fill<<<N_EDGE / 256, 256, 0, stream>>>(eidx, eidx + N_EDGE, offs, curs, csr);
  ui_prop<true><<<8000, 256, 0, stream>>>(nullptr, user_emb, item_emb, E1, offs, csr, disui);
  ui_prop<false><<<8000, 256, 0, stream>>>(E1, user_emb, item_emb, E2, offs, csr, disui);
  ui_final<<<8000, 256, 0, stream>>>(user_emb, item_emb, E1, E2, hn, out);
}

// Round 5
// 361.101 us; speedup vs baseline: 3.9163x; 1.7541x over previous
//
#include <hip/hip_runtime.h>
#include <math.h>

#define N_USER 24000
#define N_ITEM 8000
#define N_NODE 32000
#define N_EDGE 800000
#define NJC    10          // j-chunks for sim/topk
#define JCH    800         // j per chunk = 25 panels of 32
#define NEG_INF -1e30f

typedef __attribute__((ext_vector_type(8))) short bf16x8;
typedef __attribute__((ext_vector_type(4))) float f32x4;

__device__ __forceinline__ float wred_sum(float v) {
#pragma unroll
  for (int off = 32; off; off >>= 1) v += __shfl_xor(v, off, 64);
  return v;
}

__device__ __forceinline__ unsigned short f2bf(float f) {
  unsigned int u = __float_as_uint(f);
  unsigned int r = (u + 0x7fffu + ((u >> 16) & 1u)) >> 16;
  return (unsigned short)r;
}
__device__ __forceinline__ float bf2f(unsigned short h) {
  return __uint_as_float(((unsigned int)h) << 16);
}

__device__ __forceinline__ unsigned int umx(unsigned int a, unsigned int b) { return a > b ? a : b; }
__device__ __forceinline__ unsigned int umn(unsigned int a, unsigned int b) { return a < b ? a : b; }

// key encode: v19 = trunc(sim*131072 + 131080) in [0, 2^19); key = (v19<<13) | (8191-j)
__device__ __forceinline__ float key_val(unsigned int k) {
  return ((float)(int)(k >> 13) - 131080.0f) * (1.0f / 131072.0f);
}
__device__ __forceinline__ int key_idx(unsigned int k) {
  return 8191 - (int)(k & 8191u);
}

// ---------------- projection GEMM partial: P[chunk] = X[:, kc] @ W[kc, :] ----
__global__ __launch_bounds__(256) void gemm64(
    const float* __restrict__ X, const float* __restrict__ W,
    float* __restrict__ P, int K, int Klen)
{
  __shared__ float As[32 * 64];   // As[k][r]
  __shared__ float Bs[32 * 64];   // Bs[k][n]
  const int tid = threadIdx.x;
  const int m0 = blockIdx.x * 64;
  const int kc0 = blockIdx.y * Klen;
  float* out = P + (size_t)blockIdx.y * N_ITEM * 64;
  const int tr = tid >> 4, tc = tid & 15;
  float acc[4][4] = {};
  for (int k0 = kc0; k0 < kc0 + Klen; k0 += 32) {
    __syncthreads();
#pragma unroll
    for (int l = 0; l < 2; ++l) {
      int f4 = tid + l * 256;
      int r = f4 >> 3, kq = f4 & 7;        // A: 64 rows x 8 float4
      float4 a = *(const float4*)(X + (size_t)(m0 + r) * K + k0 + kq * 4);
      As[(kq * 4 + 0) * 64 + r] = a.x;
      As[(kq * 4 + 1) * 64 + r] = a.y;
      As[(kq * 4 + 2) * 64 + r] = a.z;
      As[(kq * 4 + 3) * 64 + r] = a.w;
      int kb = f4 >> 4, nq = f4 & 15;      // B: 32 rows x 16 float4
      *(float4*)(Bs + kb * 64 + nq * 4) =
          *(const float4*)(W + (size_t)(k0 + kb) * 64 + nq * 4);
    }
    __syncthreads();
#pragma unroll
    for (int k = 0; k < 32; ++k) {
      float4 a4 = *(const float4*)(As + k * 64 + tr * 4);
      float4 b4 = *(const float4*)(Bs + k * 64 + tc * 4);
      float av[4] = {a4.x, a4.y, a4.z, a4.w};
      float bv[4] = {b4.x, b4.y, b4.z, b4.w};
#pragma unroll
      for (int ri = 0; ri < 4; ++ri)
#pragma unroll
        for (int ci = 0; ci < 4; ++ci) acc[ri][ci] += av[ri] * bv[ci];
    }
  }
#pragma unroll
  for (int ri = 0; ri < 4; ++ri) {
    float4 o;
    o.x = acc[ri][0]; o.y = acc[ri][1]; o.z = acc[ri][2]; o.w = acc[ri][3];
    *(float4*)(out + (size_t)(m0 + tr * 4 + ri) * 64 + tc * 4) = o;
  }
}

// ---------------- sum nk partials + bias, L2-normalize, split bf16 hi/lo -----
__global__ __launch_bounds__(256) void norm_split(
    const float* __restrict__ P, const float* __restrict__ bias,
    unsigned short* __restrict__ Xh, unsigned short* __restrict__ Xl, int nk)
{
  int row = blockIdx.x * 4 + (threadIdx.x >> 6);
  int lane = threadIdx.x & 63;
  size_t o = (size_t)row * 64 + lane;
  float v = bias[lane];
  for (int q = 0; q < nk; ++q) v += P[(size_t)q * N_ITEM * 64 + o];
  float ss = wred_sum(v * v);
  float xn = v * rsqrtf(ss);
  unsigned short hi = f2bf(xn);
  Xh[o] = hi;
  Xl[o] = f2bf(xn - bf2f(hi));
}

// ---------------- MFMA sim + branchless u32-key top-10 -----------------------
// grid (125, NJC), block 128 (2 waves). Wave: 32 i (2x16 subtiles).
// A = j-rows (LDS dbuf panel of 32 rows), B = i-rows -> C[j_loc, i_loc].
__global__ __launch_bounds__(128) void sim_topk_mfma(
    const unsigned short* __restrict__ Xh, const unsigned short* __restrict__ Xl,
    unsigned int* __restrict__ pk)
{
  __shared__ char lds[2 * 2 * 32 * 128];   // 16 KiB: [buf][hi/lo][32 rows][128B]
  const int tid = threadIdx.x;
  const int l = tid & 63;
  const int wid = tid >> 6;
  const int ib = blockIdx.x * 64 + wid * 32;
  const int jc = blockIdx.y * JCH;

  // B-fragments (i side), loaded once. s = i-subtile, kh = K-half.
  bf16x8 bh[2][2], bl[2][2];
#pragma unroll
  for (int s = 0; s < 2; ++s) {
    int irow = ib + s * 16 + (l & 15);
    int ksl = (l >> 4) * 8;
#pragma unroll
    for (int kh = 0; kh < 2; ++kh) {
      bh[s][kh] = *(const bf16x8*)(Xh + (size_t)irow * 64 + kh * 32 + ksl);
      bl[s][kh] = *(const bf16x8*)(Xl + (size_t)irow * 64 + kh * 32 + ksl);
    }
  }

  unsigned int K0[10], K1[10];
#pragma unroll
  for (int t = 0; t < 10; ++t) { K0[t] = 0u; K1[t] = 0u; }

  auto stage = [&](int b, int p) {
#pragma unroll
    for (int s2 = 0; s2 < 2; ++s2) {
      int u = tid + s2 * 128;              // 256 16B-units per matrix
      int row = u >> 3, cb = (u & 7) * 16;
      int gr = jc + p * 32 + row;
      int4 vh = *(const int4*)(Xh + (size_t)gr * 64 + (cb >> 1));
      int4 vl = *(const int4*)(Xl + (size_t)gr * 64 + (cb >> 1));
      int bo = (row * 128 + cb) ^ ((row & 7) << 4);
      *(int4*)(lds + b * 8192 + bo) = vh;
      *(int4*)(lds + b * 8192 + 4096 + bo) = vl;
    }
  };

  stage(0, 0);
  int cur = 0;
  for (int p = 0; p < 25; ++p) {           // 25 panels x 2 j-tiles
    __syncthreads();
    if (p < 24) stage(cur ^ 1, p + 1);
    const char* ldsH = lds + cur * 8192;
    const char* ldsL = ldsH + 4096;
    f32x4 acc[2][2] = {};
#pragma unroll
    for (int t = 0; t < 2; ++t) {
      int jr = t * 16 + (l & 15);
      int sw = (jr & 7) << 4;
      int rb = jr * 128 + ((l >> 4) << 4);
      bf16x8 ah0 = *(const bf16x8*)(ldsH + (rb ^ sw));
      bf16x8 ah1 = *(const bf16x8*)(ldsH + ((rb + 64) ^ sw));
      bf16x8 al0 = *(const bf16x8*)(ldsL + (rb ^ sw));
      bf16x8 al1 = *(const bf16x8*)(ldsL + ((rb + 64) ^ sw));
#pragma unroll
      for (int s = 0; s < 2; ++s) {
        acc[t][s] = __builtin_amdgcn_mfma_f32_16x16x32_bf16(ah0, bh[s][0], acc[t][s], 0, 0, 0);
        acc[t][s] = __builtin_amdgcn_mfma_f32_16x16x32_bf16(ah1, bh[s][1], acc[t][s], 0, 0, 0);
        acc[t][s] = __builtin_amdgcn_mfma_f32_16x16x32_bf16(ah0, bl[s][0], acc[t][s], 0, 0, 0);
        acc[t][s] = __builtin_amdgcn_mfma_f32_16x16x32_bf16(ah1, bl[s][1], acc[t][s], 0, 0, 0);
        acc[t][s] = __builtin_amdgcn_mfma_f32_16x16x32_bf16(al0, bh[s][0], acc[t][s], 0, 0, 0);
        acc[t][s] = __builtin_amdgcn_mfma_f32_16x16x32_bf16(al1, bh[s][1], acc[t][s], 0, 0, 0);
      }
    }
    // branchless epilogue: build u32 keys, unconditional compare-exchange chains
    const int jg0 = jc + p * 32 + ((l >> 4) << 2);
#pragma unroll
    for (int s = 0; s < 2; ++s) {
      unsigned int* K = s ? K1 : K0;
#pragma unroll
      for (int t = 0; t < 2; ++t) {
#pragma unroll
        for (int r = 0; r < 4; ++r) {
          float f = acc[t][s][r];
          unsigned int v19 = (unsigned int)(int)(f * 131072.0f + 131080.0f);
          unsigned int key = (v19 << 13) | (unsigned int)(8191 - (jg0 + t * 16 + r));
#pragma unroll
          for (int q = 0; q < 10; ++q) {
            unsigned int mn = umn(K[q], key);
            K[q] = umx(K[q], key);
            key = mn;
          }
        }
      }
    }
    cur ^= 1;
  }

  // in-wave merge of 4 lane-groups (shfl 16/32 tournament), lanes 0..15 store
#pragma unroll
  for (int s = 0; s < 2; ++s) {
    unsigned int* K = s ? K1 : K0;
    unsigned int kv[10];
#pragma unroll
    for (int t = 0; t < 10; ++t) {
      unsigned int m = K[0];
      m = umx(m, (unsigned int)__shfl_xor((int)m, 16, 64));
      m = umx(m, (unsigned int)__shfl_xor((int)m, 32, 64));
      bool own = (K[0] == m);
#pragma unroll
      for (int q2 = 0; q2 < 9; ++q2) K[q2] = own ? K[q2 + 1] : K[q2];
      K[9] = own ? 0u : K[9];
      kv[t] = m;
    }
    int i = ib + s * 16 + (l & 15);
    if (l < 16) {
      size_t base = ((size_t)i * NJC + blockIdx.y) * 10;
#pragma unroll
      for (int t = 0; t < 10; ++t) pk[base + t] = kv[t];
    }
  }
}

// ---------------- merge 100 key candidates -> top-10 + dis -------------------
__global__ __launch_bounds__(256) void merge_topk(
    const unsigned int* __restrict__ pk,
    float* __restrict__ tv, int* __restrict__ tc, float* __restrict__ dis)
{
  int lane = threadIdx.x & 63;
  int row = blockIdx.x * 4 + (threadIdx.x >> 6);
  size_t base = (size_t)row * (NJC * 10);  // 100 = 64 + 36
  unsigned int k0 = pk[base + lane];
  unsigned int k1 = (lane < 36) ? pk[base + 64 + lane] : 0u;
  float deg = 0.f, keepv = 0.f; int keepc = 0;
  for (int t = 0; t < 10; ++t) {
    unsigned int m = umx(k0, k1);
#pragma unroll
    for (int off = 32; off; off >>= 1)
      m = umx(m, (unsigned int)__shfl_xor((int)m, off, 64));
    deg += key_val(m);
    if (k0 == m) k0 = 0u;
    else if (k1 == m) k1 = 0u;
    if (lane == t) { keepv = key_val(m); keepc = key_idx(m); }
  }
  if (lane < 10) { tv[(size_t)row * 10 + lane] = keepv; tc[(size_t)row * 10 + lane] = keepc; }
  if (lane == 0) dis[row] = deg > 0.f ? rsqrtf(deg) : 0.f;
}

// ---------------- fused SPMM (both modalities) + attention + h_norm ----------
__global__ __launch_bounds__(256) void spmm_attn(
    const float* __restrict__ tv_i, const int* __restrict__ tc_i, const float* __restrict__ dis_i,
    const float* __restrict__ ow_i, const int* __restrict__ oc_i,
    const float* __restrict__ tv_t, const int* __restrict__ tc_t, const float* __restrict__ dis_t,
    const float* __restrict__ ow_t, const int* __restrict__ oc_t,
    const float* __restrict__ item_emb,
    const float* __restrict__ Wq1, const float* __restrict__ bq1,
    const float* __restrict__ wq2, float* __restrict__ hn)
{
  __shared__ float Wlds[64 * 64];
  __shared__ float sm[4][2][64];
  int tid = threadIdx.x;
  int lane = tid & 63, wid = tid >> 6;
  int row = blockIdx.x * 4 + wid;
#pragma unroll
  for (int s = 0; s < 4; ++s) {
    int idx = tid + s * 256;
    ((float4*)Wlds)[idx] = ((const float4*)Wq1)[idx];
  }
  float a0 = 0.f, a1 = 0.f;
  {
    float disr = dis_i[row];
#pragma unroll
    for (int t = 0; t < 10; ++t) {
      int c = tc_i[(size_t)row * 10 + t];
      a0 += 0.1f * disr * tv_i[(size_t)row * 10 + t] * dis_i[c] * item_emb[(size_t)c * 64 + lane];
    }
#pragma unroll
    for (int t = 0; t < 10; ++t) {
      int c = oc_i[(size_t)row * 10 + t];
      a0 += 0.9f * ow_i[(size_t)row * 10 + t] * item_emb[(size_t)c * 64 + lane];
    }
  }
  {
    float disr = dis_t[row];
#pragma unroll
    for (int t = 0; t < 10; ++t) {
      int c = tc_t[(size_t)row * 10 + t];
      a1 += 0.1f * disr * tv_t[(size_t)row * 10 + t] * dis_t[c] * item_emb[(size_t)c * 64 + lane];
    }
#pragma unroll
    for (int t = 0; t < 10; ++t) {
      int c = oc_t[(size_t)row * 10 + t];
      a1 += 0.9f * ow_t[(size_t)row * 10 + t] * item_emb[(size_t)c * 64 + lane];
    }
  }
  sm[wid][0][lane] = a0;
  sm[wid][1][lane] = a1;
  __syncthreads();
  float y0 = bq1[lane], y1 = bq1[lane];
  for (int k = 0; k < 64; ++k) {
    float w = Wlds[k * 64 + lane];
    y0 += sm[wid][0][k] * w;
    y1 += sm[wid][1][k] * w;
  }
  float wq = wq2[lane];
  float s0 = wred_sum(tanhf(y0) * wq);
  float s1 = wred_sum(tanhf(y1) * wq);
  float mx = fmaxf(s0, s1);
  float e0 = expf(s0 - mx), e1 = expf(s1 - mx);
  float inv = 1.f / (e0 + e1);
  float h = (e0 * inv) * a0 + (e1 * inv) * a1;
  float n2 = wred_sum(h * h);
  float nrm = fmaxf(sqrtf(n2), 1e-12f);
  hn[(size_t)row * 64 + lane] = h / nrm;
}

// ---------------- UI graph helpers -------------------------------------------
__global__ void ui_zero(int* degi, int* cursor)
{
  int n = blockIdx.x * 256 + threadIdx.x;
  if (n < N_NODE) { degi[n] = 0; cursor[n] = 0; }
}

__global__ void ui_count(const int* __restrict__ r, int* degi)
{
  int e = blockIdx.x * 256 + threadIdx.x;
  if (e < N_EDGE) atomicAdd(&degi[r[e]], 1);
}

// coalesced 3-kernel scan
__global__ __launch_bounds__(256) void ui_blocksum(const int* __restrict__ degi, int* __restrict__ bsum)
{
  __shared__ int ws4[4];
  int tid = threadIdx.x;
  int v = degi[blockIdx.x * 256 + tid];
#pragma unroll
  for (int off = 32; off; off >>= 1) v += __shfl_xor(v, off, 64);
  if ((tid & 63) == 0) ws4[tid >> 6] = v;
  __syncthreads();
  if (tid == 0) bsum[blockIdx.x] = ws4[0] + ws4[1] + ws4[2] + ws4[3];
}

__global__ __launch_bounds__(128) void ui_scanb(const int* __restrict__ bsum, int* __restrict__ bbase, int* __restrict__ offs)
{
  __shared__ int s[128];
  int t = threadIdx.x;
  int v = (t < 125) ? bsum[t] : 0;
  s[t] = v;
  __syncthreads();
  for (int off = 1; off < 128; off <<= 1) {
    int tmp = (t >= off) ? s[t - off] : 0;
    __syncthreads();
    s[t] += tmp;
    __syncthreads();
  }
  if (t < 125) bbase[t] = s[t] - v;
  if (t == 127) offs[N_NODE] = s[127];
}

__global__ __launch_bounds__(256) void ui_scanc(const int* __restrict__ degi, const int* __restrict__ bbase,
                                                int* __restrict__ offs, float* __restrict__ disui)
{
  __shared__ int wt[4];
  int tid = threadIdx.x;
  int i = blockIdx.x * 256 + tid;
  int d = degi[i];
  int v = d;
#pragma unroll
  for (int off = 1; off < 64; off <<= 1) {
    int n = __shfl_up(v, off, 64);
    if ((tid & 63) >= off) v += n;
  }
  if ((tid & 63) == 63) wt[tid >> 6] = v;
  __syncthreads();
  int add = bbase[blockIdx.x];
  for (int w = 0; w < (tid >> 6); ++w) add += wt[w];
  offs[i] = add + v - d;
  disui[i] = d > 0 ? rsqrtf((float)d) : 0.f;
}

__global__ void ui_fill(const int* __restrict__ r, const int* __restrict__ c,
                        const int* __restrict__ offs, int* cursor, int* __restrict__ csr)
{
  int e = blockIdx.x * 256 + threadIdx.x;
  if (e < N_EDGE) {
    int rr = r[e];
    int pos = offs[rr] + atomicAdd(&cursor[rr], 1);
    csr[pos] = c[e];
  }
}

// wave per row; 4 edges in flight (16 lanes x float4 each); FINAL fuses mean+h
template <bool FIRST, bool FINAL>
__global__ __launch_bounds__(256) void ui_prop(
    const float* __restrict__ in, const float* __restrict__ ue,
    const float* __restrict__ ie, float* __restrict__ out,
    const int* __restrict__ offs, const int* __restrict__ csr,
    const float* __restrict__ dis, const float* __restrict__ hn)
{
  int tid = threadIdx.x;
  int lane = tid & 63, wid = tid >> 6;
  int row = blockIdx.x * 4 + wid;
  int q = lane >> 4, c4 = lane & 15;
  float4 acc = make_float4(0.f, 0.f, 0.f, 0.f);
  int e0 = offs[row], e1 = offs[row + 1];
  for (int e = e0 + q; e < e1; e += 4) {
    int cc = csr[e];
    const float* src = FIRST
        ? (cc < N_USER ? ue + (size_t)cc * 64 : ie + (size_t)(cc - N_USER) * 64)
        : in + (size_t)cc * 64;
    float4 v = *(const float4*)(src + c4 * 4);
    float d = dis[cc];
    acc.x += d * v.x; acc.y += d * v.y; acc.z += d * v.z; acc.w += d * v.w;
  }
#pragma unroll
  for (int off = 16; off <= 32; off <<= 1) {
    acc.x += __shfl_xor(acc.x, off, 64);
    acc.y += __shfl_xor(acc.y, off, 64);
    acc.z += __shfl_xor(acc.z, off, 64);
    acc.w += __shfl_xor(acc.w, off, 64);
  }
  if (q == 0) {
    float dr = dis[row];
    acc.x *= dr; acc.y *= dr; acc.z *= dr; acc.w *= dr;
    if (!FINAL) {
      *(float4*)(out + (size_t)row * 64 + c4 * 4) = acc;
    } else {
      float4 ego = (row < N_USER)
          ? *(const float4*)(ue + (size_t)row * 64 + c4 * 4)
          : *(const float4*)(ie + (size_t)(row - N_USER) * 64 + c4 * 4);
      float4 l1 = *(const float4*)(in + (size_t)row * 64 + c4 * 4);
      float4 o;
      o.x = (ego.x + l1.x + acc.x) * (1.f / 3.f);
      o.y = (ego.y + l1.y + acc.y) * (1.f / 3.f);
      o.z = (ego.z + l1.z + acc.z) * (1.f / 3.f);
      o.w = (ego.w + l1.w + acc.w) * (1.f / 3.f);
      if (row >= N_USER) {
        float4 h = *(const float4*)(hn + (size_t)(row - N_USER) * 64 + c4 * 4);
        o.x += h.x; o.y += h.y; o.z += h.z; o.w += h.w;
      }
      *(float4*)(out + (size_t)row * 64 + c4 * 4) = o;
    }
  }
}

// ---------------- host driver ------------------------------------------------
extern "C" void kernel_launch(void* const* d_in, const int* in_sizes, int n_in,
                              void* d_out, int out_size, void* d_ws, size_t ws_size,
                              hipStream_t stream)
{
  (void)in_sizes; (void)n_in; (void)out_size; (void)ws_size;
  const float* user_emb = (const float*)d_in[0];
  const float* item_emb = (const float*)d_in[1];
  const float* v_feat   = (const float*)d_in[2];
  const float* t_feat   = (const float*)d_in[3];
  const float* W_v      = (const float*)d_in[4];
  const float* b_v      = (const float*)d_in[5];
  const float* W_t      = (const float*)d_in[6];
  const float* b_t      = (const float*)d_in[7];
  const float* Wq1      = (const float*)d_in[8];
  const float* bq1      = (const float*)d_in[9];
  const float* wq2      = (const float*)d_in[10];
  const float* ow_i     = (const float*)d_in[11];
  const float* ow_t     = (const float*)d_in[12];
  const int*   eidx     = (const int*)d_in[13];
  const int*   oc_i     = (const int*)d_in[14];
  const int*   oc_t     = (const int*)d_in[15];
  float* out = (float*)d_out;

  char* wp = (char*)d_ws;
  auto alloc = [&](size_t bytes) -> void* {
    void* p = (void*)wp;
    wp += (bytes + 255) & ~(size_t)255;
    return p;
  };
  // big buffers: key candidates first, later aliased as ego layer buffer
  unsigned int* BIG0 = (unsigned int*)alloc((size_t)N_NODE * 64 * 4 + 1024);
  float*        BIG1 = (float*)alloc((size_t)N_NODE * 64 * 4 + 1024);
  unsigned int* pk = BIG0;      // needs 8000*100*4 = 3.2 MB
  float* E1 = BIG1;

  float*          Pp  = (float*)alloc((size_t)4 * N_ITEM * 64 * 4);  // 4 k-chunk partials
  unsigned short* Xh  = (unsigned short*)alloc((size_t)N_ITEM * 64 * 2);
  unsigned short* Xl  = (unsigned short*)alloc((size_t)N_ITEM * 64 * 2);
  float* tv_i  = (float*)alloc((size_t)N_ITEM * 10 * 4);
  int*   tc_i  = (int*)  alloc((size_t)N_ITEM * 10 * 4);
  float* dis_i = (float*)alloc((size_t)N_ITEM * 4);
  float* tv_t  = (float*)alloc((size_t)N_ITEM * 10 * 4);
  int*   tc_t  = (int*)  alloc((size_t)N_ITEM * 10 * 4);
  float* dis_t = (float*)alloc((size_t)N_ITEM * 4);
  float* hn    = (float*)alloc((size_t)N_ITEM * 64 * 4);
  int*   degi  = (int*)  alloc((size_t)N_NODE * 4);
  int*   curs  = (int*)  alloc((size_t)N_NODE * 4);
  int*   offs  = (int*)  alloc((size_t)(N_NODE + 1) * 4);
  float* disui = (float*)alloc((size_t)N_NODE * 4);
  int*   csr   = (int*)  alloc((size_t)N_EDGE * 4);
  int*   bsum  = (int*)  alloc((size_t)128 * 4);
  int*   bbase = (int*)  alloc((size_t)128 * 4);

  // ---- image modality ----
  gemm64<<<dim3(125, 4), 256, 0, stream>>>(v_feat, W_v, Pp, 2048, 512);
  norm_split<<<2000, 256, 0, stream>>>(Pp, b_v, Xh, Xl, 4);
  sim_topk_mfma<<<dim3(125, NJC), 128, 0, stream>>>(Xh, Xl, pk);
  merge_topk<<<2000, 256, 0, stream>>>(pk, tv_i, tc_i, dis_i);
  // ---- text modality ----
  gemm64<<<dim3(125, 2), 256, 0, stream>>>(t_feat, W_t, Pp, 384, 192);
  norm_split<<<2000, 256, 0, stream>>>(Pp, b_t, Xh, Xl, 2);
  sim_topk_mfma<<<dim3(125, NJC), 128, 0, stream>>>(Xh, Xl, pk);
  merge_topk<<<2000, 256, 0, stream>>>(pk, tv_t, tc_t, dis_t);
  // ---- fused SPMM + attention + h_norm ----
  spmm_attn<<<2000, 256, 0, stream>>>(tv_i, tc_i, dis_i, ow_i, oc_i,
                                      tv_t, tc_t, dis_t, ow_t, oc_t,
                                      item_emb, Wq1, bq1, wq2, hn);
  // ---- user-item graph ----
  ui_zero<<<125, 256, 0, stream>>>(degi, curs);
  ui_count<<<N_EDGE / 256, 256, 0, stream>>>(eidx, degi);
  ui_blocksum<<<125, 256, 0, stream>>>(degi, bsum);
  ui_scanb<<<1, 128, 0, stream>>>(bsum, bbase, offs);
  ui_scanc<<<125, 256, 0, stream>>>(degi, bbase, offs, disui);
  ui_fill<<<N_EDGE / 256, 256, 0, stream>>>(eidx, eidx + N_EDGE, offs, curs, csr);
  ui_prop<true, false><<<8000, 256, 0, stream>>>(nullptr, user_emb, item_emb, E1, offs, csr, disui, nullptr);
  ui_prop<false, true><<<8000, 256, 0, stream>>>(E1, user_emb, item_emb, out, offs, csr, disui, hn);
}

// Round 6
// 320.009 us; speedup vs baseline: 4.4192x; 1.1284x over previous
//
#include <hip/hip_runtime.h>
#include <math.h>

#define N_USER 24000
#define N_ITEM 8000
#define N_NODE 32000
#define N_EDGE 800000
#define NJC    16          // j-chunks for sim/topk
#define JCH    512         // j per chunk = 16 panels of 32 (last chunk masked)

typedef __attribute__((ext_vector_type(8))) short bf16x8;
typedef __attribute__((ext_vector_type(4))) float f32x4;

__device__ __forceinline__ float wred_sum(float v) {
#pragma unroll
  for (int off = 32; off; off >>= 1) v += __shfl_xor(v, off, 64);
  return v;
}

__device__ __forceinline__ unsigned short f2bf(float f) {
  unsigned int u = __float_as_uint(f);
  unsigned int r = (u + 0x7fffu + ((u >> 16) & 1u)) >> 16;
  return (unsigned short)r;
}
__device__ __forceinline__ float bf2f(unsigned short h) {
  return __uint_as_float(((unsigned int)h) << 16);
}

__device__ __forceinline__ unsigned int umx(unsigned int a, unsigned int b) { return a > b ? a : b; }
__device__ __forceinline__ unsigned int umn(unsigned int a, unsigned int b) { return a < b ? a : b; }

// key encode: v19 = trunc(sim*131072 + 131080) in [0, 2^19); key = (v19<<13) | (8191-j)
__device__ __forceinline__ float key_val(unsigned int k) {
  return ((float)(int)(k >> 13) - 131080.0f) * (1.0f / 131072.0f);
}
__device__ __forceinline__ int key_idx(unsigned int k) {
  return 8191 - (int)(k & 8191u);
}

// ---------------- dual projection GEMM partials ------------------------------
// grid (125, 11): y<8 -> image chunk y (Klen 256); y>=8 -> text chunk y-8 (Klen 128)
__global__ __launch_bounds__(256) void gemm_dual(
    const float* __restrict__ Xi, const float* __restrict__ Wi,
    const float* __restrict__ Xt, const float* __restrict__ Wt,
    float* __restrict__ Pi, float* __restrict__ Pt)
{
  __shared__ float As[32 * 64];   // As[k][r]
  __shared__ float Bs[32 * 64];   // Bs[k][n]
  const int tid = threadIdx.x;
  const int m0 = blockIdx.x * 64;
  const int cy = blockIdx.y;
  const float* X; const float* W; float* out; int K, kc0, Klen;
  if (cy < 8) { X = Xi; W = Wi; K = 2048; Klen = 256; kc0 = cy * 256;
                out = Pi + (size_t)cy * N_ITEM * 64; }
  else        { X = Xt; W = Wt; K = 384;  Klen = 128; kc0 = (cy - 8) * 128;
                out = Pt + (size_t)(cy - 8) * N_ITEM * 64; }
  const int tr = tid >> 4, tc = tid & 15;
  float acc[4][4] = {};
  for (int k0 = kc0; k0 < kc0 + Klen; k0 += 32) {
    __syncthreads();
#pragma unroll
    for (int l = 0; l < 2; ++l) {
      int f4 = tid + l * 256;
      int r = f4 >> 3, kq = f4 & 7;        // A: 64 rows x 8 float4
      float4 a = *(const float4*)(X + (size_t)(m0 + r) * K + k0 + kq * 4);
      As[(kq * 4 + 0) * 64 + r] = a.x;
      As[(kq * 4 + 1) * 64 + r] = a.y;
      As[(kq * 4 + 2) * 64 + r] = a.z;
      As[(kq * 4 + 3) * 64 + r] = a.w;
      int kb = f4 >> 4, nq = f4 & 15;      // B: 32 rows x 16 float4
      *(float4*)(Bs + kb * 64 + nq * 4) =
          *(const float4*)(W + (size_t)(k0 + kb) * 64 + nq * 4);
    }
    __syncthreads();
#pragma unroll
    for (int k = 0; k < 32; ++k) {
      float4 a4 = *(const float4*)(As + k * 64 + tr * 4);
      float4 b4 = *(const float4*)(Bs + k * 64 + tc * 4);
      float av[4] = {a4.x, a4.y, a4.z, a4.w};
      float bv[4] = {b4.x, b4.y, b4.z, b4.w};
#pragma unroll
      for (int ri = 0; ri < 4; ++ri)
#pragma unroll
        for (int ci = 0; ci < 4; ++ci) acc[ri][ci] += av[ri] * bv[ci];
    }
  }
#pragma unroll
  for (int ri = 0; ri < 4; ++ri) {
    float4 o;
    o.x = acc[ri][0]; o.y = acc[ri][1]; o.z = acc[ri][2]; o.w = acc[ri][3];
    *(float4*)(out + (size_t)(m0 + tr * 4 + ri) * 64 + tc * 4) = o;
  }
}

// ---------------- dual: sum partials + bias, L2-normalize, split bf16 --------
__global__ __launch_bounds__(256) void norm_dual(
    const float* __restrict__ Pi, const float* __restrict__ bi,
    unsigned short* __restrict__ Xhi, unsigned short* __restrict__ Xli,
    const float* __restrict__ Pt, const float* __restrict__ bt,
    unsigned short* __restrict__ Xht, unsigned short* __restrict__ Xlt)
{
  const float* P; const float* bias; unsigned short *Xh, *Xl; int nk;
  if (blockIdx.y == 0) { P = Pi; bias = bi; Xh = Xhi; Xl = Xli; nk = 8; }
  else                 { P = Pt; bias = bt; Xh = Xht; Xl = Xlt; nk = 3; }
  int row = blockIdx.x * 4 + (threadIdx.x >> 6);
  int lane = threadIdx.x & 63;
  size_t o = (size_t)row * 64 + lane;
  float v = bias[lane];
  for (int q = 0; q < nk; ++q) v += P[(size_t)q * N_ITEM * 64 + o];
  float ss = wred_sum(v * v);
  float xn = v * rsqrtf(ss);
  unsigned short hi = f2bf(xn);
  Xh[o] = hi;
  Xl[o] = f2bf(xn - bf2f(hi));
}

// ---------------- MFMA sim + branchless u32-key top-10, both modalities ------
// grid (63, NJC, 2), block 256 (4 waves, 128 i). Wave: 32 i (2x16 subtiles).
__global__ __launch_bounds__(256) void sim_topk_mfma(
    const unsigned short* __restrict__ Xhi, const unsigned short* __restrict__ Xli,
    const unsigned short* __restrict__ Xht, const unsigned short* __restrict__ Xlt,
    unsigned int* __restrict__ pk)
{
  __shared__ char lds[2 * 2 * 32 * 128];   // 16 KiB: [buf][hi/lo][32 rows][128B]
  const unsigned short* Xh = blockIdx.z ? Xht : Xhi;
  const unsigned short* Xl = blockIdx.z ? Xlt : Xli;
  unsigned int* pkm = pk + (size_t)blockIdx.z * N_ITEM * (NJC * 10);

  const int tid = threadIdx.x;
  const int l = tid & 63;
  const int wid = tid >> 6;
  const int ib = blockIdx.x * 128 + wid * 32;
  const int jc = blockIdx.y * JCH;

  // B-fragments (i side), loaded once. s = i-subtile, kh = K-half.
  bf16x8 bh[2][2], bl[2][2];
#pragma unroll
  for (int s = 0; s < 2; ++s) {
    int irow = ib + s * 16 + (l & 15);
    if (irow > N_ITEM - 1) irow = N_ITEM - 1;
    int ksl = (l >> 4) * 8;
#pragma unroll
    for (int kh = 0; kh < 2; ++kh) {
      bh[s][kh] = *(const bf16x8*)(Xh + (size_t)irow * 64 + kh * 32 + ksl);
      bl[s][kh] = *(const bf16x8*)(Xl + (size_t)irow * 64 + kh * 32 + ksl);
    }
  }

  unsigned int K0[10], K1[10];
#pragma unroll
  for (int t = 0; t < 10; ++t) { K0[t] = 0u; K1[t] = 0u; }

  auto stage = [&](int b, int p) {
    int row = tid >> 3, cb = (tid & 7) * 16;   // 256 16B-units per matrix
    int gr = jc + p * 32 + row;
    if (gr > N_ITEM - 1) gr = N_ITEM - 1;
    int4 vh = *(const int4*)(Xh + (size_t)gr * 64 + (cb >> 1));
    int4 vl = *(const int4*)(Xl + (size_t)gr * 64 + (cb >> 1));
    int bo = (row * 128 + cb) ^ ((row & 7) << 4);
    *(int4*)(lds + b * 8192 + bo) = vh;
    *(int4*)(lds + b * 8192 + 4096 + bo) = vl;
  };

  stage(0, 0);
  int cur = 0;
  for (int p = 0; p < 16; ++p) {           // 16 panels x 2 j-tiles
    __syncthreads();
    if (p < 15) stage(cur ^ 1, p + 1);
    const char* ldsH = lds + cur * 8192;
    const char* ldsL = ldsH + 4096;
    f32x4 acc[2][2] = {};
#pragma unroll
    for (int t = 0; t < 2; ++t) {
      int jr = t * 16 + (l & 15);
      int sw = (jr & 7) << 4;
      int rb = jr * 128 + ((l >> 4) << 4);
      bf16x8 ah0 = *(const bf16x8*)(ldsH + (rb ^ sw));
      bf16x8 ah1 = *(const bf16x8*)(ldsH + ((rb + 64) ^ sw));
      bf16x8 al0 = *(const bf16x8*)(ldsL + (rb ^ sw));
      bf16x8 al1 = *(const bf16x8*)(ldsL + ((rb + 64) ^ sw));
#pragma unroll
      for (int s = 0; s < 2; ++s) {
        acc[t][s] = __builtin_amdgcn_mfma_f32_16x16x32_bf16(ah0, bh[s][0], acc[t][s], 0, 0, 0);
        acc[t][s] = __builtin_amdgcn_mfma_f32_16x16x32_bf16(ah1, bh[s][1], acc[t][s], 0, 0, 0);
        acc[t][s] = __builtin_amdgcn_mfma_f32_16x16x32_bf16(ah0, bl[s][0], acc[t][s], 0, 0, 0);
        acc[t][s] = __builtin_amdgcn_mfma_f32_16x16x32_bf16(ah1, bl[s][1], acc[t][s], 0, 0, 0);
        acc[t][s] = __builtin_amdgcn_mfma_f32_16x16x32_bf16(al0, bh[s][0], acc[t][s], 0, 0, 0);
        acc[t][s] = __builtin_amdgcn_mfma_f32_16x16x32_bf16(al1, bh[s][1], acc[t][s], 0, 0, 0);
      }
    }
    // branchless epilogue: u32 keys through compare-exchange chains
    const int jg0 = jc + p * 32 + ((l >> 4) << 2);
#pragma unroll
    for (int s = 0; s < 2; ++s) {
      unsigned int* K = s ? K1 : K0;
#pragma unroll
      for (int t = 0; t < 2; ++t) {
#pragma unroll
        for (int r = 0; r < 4; ++r) {
          int jj = jg0 + t * 16 + r;
          float f = acc[t][s][r];
          unsigned int v19 = (unsigned int)(int)(f * 131072.0f + 131080.0f);
          unsigned int key = (v19 << 13) | (unsigned int)(8191 - jj);
          key = (jj < N_ITEM) ? key : 0u;
#pragma unroll
          for (int q = 0; q < 10; ++q) {
            unsigned int mn = umn(K[q], key);
            K[q] = umx(K[q], key);
            key = mn;
          }
        }
      }
    }
    cur ^= 1;
  }

  // in-wave merge of 4 lane-groups (shfl 16/32 tournament), lanes 0..15 store
#pragma unroll
  for (int s = 0; s < 2; ++s) {
    unsigned int* K = s ? K1 : K0;
    unsigned int kv[10];
#pragma unroll
    for (int t = 0; t < 10; ++t) {
      unsigned int m = K[0];
      m = umx(m, (unsigned int)__shfl_xor((int)m, 16, 64));
      m = umx(m, (unsigned int)__shfl_xor((int)m, 32, 64));
      bool own = (K[0] == m);
#pragma unroll
      for (int q2 = 0; q2 < 9; ++q2) K[q2] = own ? K[q2 + 1] : K[q2];
      K[9] = own ? 0u : K[9];
      kv[t] = m;
    }
    int i = ib + s * 16 + (l & 15);
    if (l < 16 && i < N_ITEM) {
      size_t base = ((size_t)i * NJC + blockIdx.y) * 10;
#pragma unroll
      for (int t = 0; t < 10; ++t) pkm[base + t] = kv[t];
    }
  }
}

// ---------------- merge 160 key candidates -> top-10 + dis (both mods) -------
__global__ __launch_bounds__(256) void merge_topk(
    const unsigned int* __restrict__ pk,
    float* __restrict__ tv_i, int* __restrict__ tc_i, float* __restrict__ dis_i,
    float* __restrict__ tv_t, int* __restrict__ tc_t, float* __restrict__ dis_t)
{
  float* tv; int* tc; float* dis;
  if (blockIdx.y == 0) { tv = tv_i; tc = tc_i; dis = dis_i; }
  else                 { tv = tv_t; tc = tc_t; dis = dis_t; }
  int lane = threadIdx.x & 63;
  int row = blockIdx.x * 4 + (threadIdx.x >> 6);
  size_t base = (size_t)blockIdx.y * N_ITEM * (NJC * 10) + (size_t)row * (NJC * 10);
  unsigned int k0 = pk[base + lane];
  unsigned int k1 = pk[base + 64 + lane];
  unsigned int k2 = (lane < 32) ? pk[base + 128 + lane] : 0u;
  float deg = 0.f, keepv = 0.f; int keepc = 0;
  for (int t = 0; t < 10; ++t) {
    unsigned int m = umx(umx(k0, k1), k2);
#pragma unroll
    for (int off = 32; off; off >>= 1)
      m = umx(m, (unsigned int)__shfl_xor((int)m, off, 64));
    deg += key_val(m);
    if (k0 == m) k0 = 0u;
    else if (k1 == m) k1 = 0u;
    else if (k2 == m) k2 = 0u;
    if (lane == t) { keepv = key_val(m); keepc = key_idx(m); }
  }
  if (lane < 10) { tv[(size_t)row * 10 + lane] = keepv; tc[(size_t)row * 10 + lane] = keepc; }
  if (lane == 0) dis[row] = deg > 0.f ? rsqrtf(deg) : 0.f;
}

// ---------------- fused SPMM (both modalities) + attention + h_norm ----------
__global__ __launch_bounds__(256) void spmm_attn(
    const float* __restrict__ tv_i, const int* __restrict__ tc_i, const float* __restrict__ dis_i,
    const float* __restrict__ ow_i, const int* __restrict__ oc_i,
    const float* __restrict__ tv_t, const int* __restrict__ tc_t, const float* __restrict__ dis_t,
    const float* __restrict__ ow_t, const int* __restrict__ oc_t,
    const float* __restrict__ item_emb,
    const float* __restrict__ Wq1, const float* __restrict__ bq1,
    const float* __restrict__ wq2, float* __restrict__ hn)
{
  __shared__ float Wlds[64 * 64];
  __shared__ float sm[4][2][64];
  int tid = threadIdx.x;
  int lane = tid & 63, wid = tid >> 6;
  int row = blockIdx.x * 4 + wid;
#pragma unroll
  for (int s = 0; s < 4; ++s) {
    int idx = tid + s * 256;
    ((float4*)Wlds)[idx] = ((const float4*)Wq1)[idx];
  }
  float a0 = 0.f, a1 = 0.f;
  {
    float disr = dis_i[row];
#pragma unroll
    for (int t = 0; t < 10; ++t) {
      int c = tc_i[(size_t)row * 10 + t];
      a0 += 0.1f * disr * tv_i[(size_t)row * 10 + t] * dis_i[c] * item_emb[(size_t)c * 64 + lane];
    }
#pragma unroll
    for (int t = 0; t < 10; ++t) {
      int c = oc_i[(size_t)row * 10 + t];
      a0 += 0.9f * ow_i[(size_t)row * 10 + t] * item_emb[(size_t)c * 64 + lane];
    }
  }
  {
    float disr = dis_t[row];
#pragma unroll
    for (int t = 0; t < 10; ++t) {
      int c = tc_t[(size_t)row * 10 + t];
      a1 += 0.1f * disr * tv_t[(size_t)row * 10 + t] * dis_t[c] * item_emb[(size_t)c * 64 + lane];
    }
#pragma unroll
    for (int t = 0; t < 10; ++t) {
      int c = oc_t[(size_t)row * 10 + t];
      a1 += 0.9f * ow_t[(size_t)row * 10 + t] * item_emb[(size_t)c * 64 + lane];
    }
  }
  sm[wid][0][lane] = a0;
  sm[wid][1][lane] = a1;
  __syncthreads();
  float y0 = bq1[lane], y1 = bq1[lane];
  for (int k = 0; k < 64; ++k) {
    float w = Wlds[k * 64 + lane];
    y0 += sm[wid][0][k] * w;
    y1 += sm[wid][1][k] * w;
  }
  float wq = wq2[lane];
  float s0 = wred_sum(tanhf(y0) * wq);
  float s1 = wred_sum(tanhf(y1) * wq);
  float mx = fmaxf(s0, s1);
  float e0 = expf(s0 - mx), e1 = expf(s1 - mx);
  float inv = 1.f / (e0 + e1);
  float h = (e0 * inv) * a0 + (e1 * inv) * a1;
  float n2 = wred_sum(h * h);
  float nrm = fmaxf(sqrtf(n2), 1e-12f);
  hn[(size_t)row * 64 + lane] = h / nrm;
}

// ---------------- UI graph helpers -------------------------------------------
__global__ void ui_zero(int* degi, int* cursor)
{
  int n = blockIdx.x * 256 + threadIdx.x;
  if (n < N_NODE) { degi[n] = 0; cursor[n] = 0; }
}

__global__ void ui_count(const int* __restrict__ r, int* degi)
{
  int e = blockIdx.x * 256 + threadIdx.x;
  if (e < N_EDGE) atomicAdd(&degi[r[e]], 1);
}

// coalesced 3-kernel scan
__global__ __launch_bounds__(256) void ui_blocksum(const int* __restrict__ degi, int* __restrict__ bsum)
{
  __shared__ int ws4[4];
  int tid = threadIdx.x;
  int v = degi[blockIdx.x * 256 + tid];
#pragma unroll
  for (int off = 32; off; off >>= 1) v += __shfl_xor(v, off, 64);
  if ((tid & 63) == 0) ws4[tid >> 6] = v;
  __syncthreads();
  if (tid == 0) bsum[blockIdx.x] = ws4[0] + ws4[1] + ws4[2] + ws4[3];
}

__global__ __launch_bounds__(128) void ui_scanb(const int* __restrict__ bsum, int* __restrict__ bbase, int* __restrict__ offs)
{
  __shared__ int s[128];
  int t = threadIdx.x;
  int v = (t < 125) ? bsum[t] : 0;
  s[t] = v;
  __syncthreads();
  for (int off = 1; off < 128; off <<= 1) {
    int tmp = (t >= off) ? s[t - off] : 0;
    __syncthreads();
    s[t] += tmp;
    __syncthreads();
  }
  if (t < 125) bbase[t] = s[t] - v;
  if (t == 127) offs[N_NODE] = s[127];
}

__global__ __launch_bounds__(256) void ui_scanc(const int* __restrict__ degi, const int* __restrict__ bbase,
                                                int* __restrict__ offs, float* __restrict__ disui)
{
  __shared__ int wt[4];
  int tid = threadIdx.x;
  int i = blockIdx.x * 256 + tid;
  int d = degi[i];
  int v = d;
#pragma unroll
  for (int off = 1; off < 64; off <<= 1) {
    int n = __shfl_up(v, off, 64);
    if ((tid & 63) >= off) v += n;
  }
  if ((tid & 63) == 63) wt[tid >> 6] = v;
  __syncthreads();
  int add = bbase[blockIdx.x];
  for (int w = 0; w < (tid >> 6); ++w) add += wt[w];
  offs[i] = add + v - d;
  disui[i] = d > 0 ? rsqrtf((float)d) : 0.f;
}

__global__ void ui_fill(const int* __restrict__ r, const int* __restrict__ c,
                        const int* __restrict__ offs, int* cursor, int* __restrict__ csr)
{
  int e = blockIdx.x * 256 + threadIdx.x;
  if (e < N_EDGE) {
    int rr = r[e];
    int pos = offs[rr] + atomicAdd(&cursor[rr], 1);
    csr[pos] = c[e];
  }
}

// wave per row; 4 edges in flight (16 lanes x float4 each); FINAL fuses mean+h
template <bool FIRST, bool FINAL>
__global__ __launch_bounds__(256) void ui_prop(
    const float* __restrict__ in, const float* __restrict__ ue,
    const float* __restrict__ ie, float* __restrict__ out,
    const int* __restrict__ offs, const int* __restrict__ csr,
    const float* __restrict__ dis, const float* __restrict__ hn)
{
  int tid = threadIdx.x;
  int lane = tid & 63, wid = tid >> 6;
  int row = blockIdx.x * 4 + wid;
  int q = lane >> 4, c4 = lane & 15;
  float4 acc = make_float4(0.f, 0.f, 0.f, 0.f);
  int e0 = offs[row], e1 = offs[row + 1];
  for (int e = e0 + q; e < e1; e += 4) {
    int cc = csr[e];
    const float* src = FIRST
        ? (cc < N_USER ? ue + (size_t)cc * 64 : ie + (size_t)(cc - N_USER) * 64)
        : in + (size_t)cc * 64;
    float4 v = *(const float4*)(src + c4 * 4);
    float d = dis[cc];
    acc.x += d * v.x; acc.y += d * v.y; acc.z += d * v.z; acc.w += d * v.w;
  }
#pragma unroll
  for (int off = 16; off <= 32; off <<= 1) {
    acc.x += __shfl_xor(acc.x, off, 64);
    acc.y += __shfl_xor(acc.y, off, 64);
    acc.z += __shfl_xor(acc.z, off, 64);
    acc.w += __shfl_xor(acc.w, off, 64);
  }
  if (q == 0) {
    float dr = dis[row];
    acc.x *= dr; acc.y *= dr; acc.z *= dr; acc.w *= dr;
    if (!FINAL) {
      *(float4*)(out + (size_t)row * 64 + c4 * 4) = acc;
    } else {
      float4 ego = (row < N_USER)
          ? *(const float4*)(ue + (size_t)row * 64 + c4 * 4)
          : *(const float4*)(ie + (size_t)(row - N_USER) * 64 + c4 * 4);
      float4 l1 = *(const float4*)(in + (size_t)row * 64 + c4 * 4);
      float4 o;
      o.x = (ego.x + l1.x + acc.x) * (1.f / 3.f);
      o.y = (ego.y + l1.y + acc.y) * (1.f / 3.f);
      o.z = (ego.z + l1.z + acc.z) * (1.f / 3.f);
      o.w = (ego.w + l1.w + acc.w) * (1.f / 3.f);
      if (row >= N_USER) {
        float4 h = *(const float4*)(hn + (size_t)(row - N_USER) * 64 + c4 * 4);
        o.x += h.x; o.y += h.y; o.z += h.z; o.w += h.w;
      }
      *(float4*)(out + (size_t)row * 64 + c4 * 4) = o;
    }
  }
}

// ---------------- host driver ------------------------------------------------
extern "C" void kernel_launch(void* const* d_in, const int* in_sizes, int n_in,
                              void* d_out, int out_size, void* d_ws, size_t ws_size,
                              hipStream_t stream)
{
  (void)in_sizes; (void)n_in; (void)out_size; (void)ws_size;
  const float* user_emb = (const float*)d_in[0];
  const float* item_emb = (const float*)d_in[1];
  const float* v_feat   = (const float*)d_in[2];
  const float* t_feat   = (const float*)d_in[3];
  const float* W_v      = (const float*)d_in[4];
  const float* b_v      = (const float*)d_in[5];
  const float* W_t      = (const float*)d_in[6];
  const float* b_t      = (const float*)d_in[7];
  const float* Wq1      = (const float*)d_in[8];
  const float* bq1      = (const float*)d_in[9];
  const float* wq2      = (const float*)d_in[10];
  const float* ow_i     = (const float*)d_in[11];
  const float* ow_t     = (const float*)d_in[12];
  const int*   eidx     = (const int*)d_in[13];
  const int*   oc_i     = (const int*)d_in[14];
  const int*   oc_t     = (const int*)d_in[15];
  float* out = (float*)d_out;

  char* wp = (char*)d_ws;
  auto alloc = [&](size_t bytes) -> void* {
    void* p = (void*)wp;
    wp += (bytes + 255) & ~(size_t)255;
    return p;
  };
  // region A: Pp_i (8 x 2.05 MB) -> later pk (2 x 5.12 MB)
  char* regionA = (char*)alloc((size_t)8 * N_ITEM * 64 * 4 + 1024);
  // region B: Pp_t (3 x 2.05 MB) -> later E1 (8.19 MB)
  char* regionB = (char*)alloc((size_t)N_NODE * 64 * 4 + 1024);
  float* Pp_i = (float*)regionA;
  float* Pp_t = (float*)regionB;
  unsigned int* pk = (unsigned int*)regionA;    // alive after norm_dual
  float* E1 = (float*)regionB;                  // alive after merge/spmm

  unsigned short* Xhi = (unsigned short*)alloc((size_t)N_ITEM * 64 * 2);
  unsigned short* Xli = (unsigned short*)alloc((size_t)N_ITEM * 64 * 2);
  unsigned short* Xht = (unsigned short*)alloc((size_t)N_ITEM * 64 * 2);
  unsigned short* Xlt = (unsigned short*)alloc((size_t)N_ITEM * 64 * 2);
  float* tv_i  = (float*)alloc((size_t)N_ITEM * 10 * 4);
  int*   tc_i  = (int*)  alloc((size_t)N_ITEM * 10 * 4);
  float* dis_i = (float*)alloc((size_t)N_ITEM * 4);
  float* tv_t  = (float*)alloc((size_t)N_ITEM * 10 * 4);
  int*   tc_t  = (int*)  alloc((size_t)N_ITEM * 10 * 4);
  float* dis_t = (float*)alloc((size_t)N_ITEM * 4);
  float* hn    = (float*)alloc((size_t)N_ITEM * 64 * 4);
  int*   degi  = (int*)  alloc((size_t)N_NODE * 4);
  int*   curs  = (int*)  alloc((size_t)N_NODE * 4);
  int*   offs  = (int*)  alloc((size_t)(N_NODE + 1) * 4);
  float* disui = (float*)alloc((size_t)N_NODE * 4);
  int*   csr   = (int*)  alloc((size_t)N_EDGE * 4);
  int*   bsum  = (int*)  alloc((size_t)128 * 4);
  int*   bbase = (int*)  alloc((size_t)128 * 4);

  // ---- projections (both modalities, one launch) ----
  gemm_dual<<<dim3(125, 11), 256, 0, stream>>>(v_feat, W_v, t_feat, W_t, Pp_i, Pp_t);
  norm_dual<<<dim3(2000, 2), 256, 0, stream>>>(Pp_i, b_v, Xhi, Xli, Pp_t, b_t, Xht, Xlt);
  // ---- sim + topk (both modalities, one launch) ----
  sim_topk_mfma<<<dim3(63, NJC, 2), 256, 0, stream>>>(Xhi, Xli, Xht, Xlt, pk);
  merge_topk<<<dim3(2000, 2), 256, 0, stream>>>(pk, tv_i, tc_i, dis_i, tv_t, tc_t, dis_t);
  // ---- fused SPMM + attention + h_norm ----
  spmm_attn<<<2000, 256, 0, stream>>>(tv_i, tc_i, dis_i, ow_i, oc_i,
                                      tv_t, tc_t, dis_t, ow_t, oc_t,
                                      item_emb, Wq1, bq1, wq2, hn);
  // ---- user-item graph ----
  ui_zero<<<125, 256, 0, stream>>>(degi, curs);
  ui_count<<<N_EDGE / 256, 256, 0, stream>>>(eidx, degi);
  ui_blocksum<<<125, 256, 0, stream>>>(degi, bsum);
  ui_scanb<<<1, 128, 0, stream>>>(bsum, bbase, offs);
  ui_scanc<<<125, 256, 0, stream>>>(degi, bbase, offs, disui);
  ui_fill<<<N_EDGE / 256, 256, 0, stream>>>(eidx, eidx + N_EDGE, offs, curs, csr);
  ui_prop<true, false><<<8000, 256, 0, stream>>>(nullptr, user_emb, item_emb, E1, offs, csr, disui, nullptr);
  ui_prop<false, true><<<8000, 256, 0, stream>>>(E1, user_emb, item_emb, out, offs, csr, disui, hn);
}

// Round 7
// 308.256 us; speedup vs baseline: 4.5877x; 1.0381x over previous
//
#include <hip/hip_runtime.h>
#include <math.h>

#define N_USER 24000
#define N_ITEM 8000
#define N_NODE 32000
#define N_EDGE 800000
#define NJC    16          // j-chunks for sim/topk
#define JCH    512         // j per chunk = 16 panels of 32 (last chunk masked)

typedef __attribute__((ext_vector_type(8))) short bf16x8;
typedef __attribute__((ext_vector_type(4))) float f32x4;

__device__ __forceinline__ float wred_sum(float v) {
#pragma unroll
  for (int off = 32; off; off >>= 1) v += __shfl_xor(v, off, 64);
  return v;
}

__device__ __forceinline__ unsigned short f2bf(float f) {
  unsigned int u = __float_as_uint(f);
  unsigned int r = (u + 0x7fffu + ((u >> 16) & 1u)) >> 16;
  return (unsigned short)r;
}
__device__ __forceinline__ float bf2f(unsigned short h) {
  return __uint_as_float(((unsigned int)h) << 16);
}

__device__ __forceinline__ unsigned int umx(unsigned int a, unsigned int b) { return a > b ? a : b; }
__device__ __forceinline__ unsigned int umn(unsigned int a, unsigned int b) { return a < b ? a : b; }

// key encode: v19 = trunc(sim*131072 + 131080) in [0, 2^19); key = (v19<<13) | (8191-j)
__device__ __forceinline__ float key_val(unsigned int k) {
  return ((float)(int)(k >> 13) - 131080.0f) * (1.0f / 131072.0f);
}
__device__ __forceinline__ int key_idx(unsigned int k) {
  return 8191 - (int)(k & 8191u);
}

// ---------------- dual projection GEMM partials, 128x64 tile -----------------
// grid (63, 11): y<8 -> image chunk y (Klen 256); y>=8 -> text chunk y-8 (Klen 128)
#define ASTR 132
__global__ __launch_bounds__(256) void gemm_dual(
    const float* __restrict__ Xi, const float* __restrict__ Wi,
    const float* __restrict__ Xt, const float* __restrict__ Wt,
    float* __restrict__ Pi, float* __restrict__ Pt)
{
  __shared__ float As[32 * ASTR];   // As[k][r], stride 132 (aligned b128 reads)
  __shared__ float Bs[32 * 64];     // Bs[k][n]
  const int tid = threadIdx.x;
  const int m0 = blockIdx.x * 128;
  const int cy = blockIdx.y;
  const float* X; const float* W; float* out; int K, kc0, Klen;
  if (cy < 8) { X = Xi; W = Wi; K = 2048; Klen = 256; kc0 = cy * 256;
                out = Pi + (size_t)cy * N_ITEM * 64; }
  else        { X = Xt; W = Wt; K = 384;  Klen = 128; kc0 = (cy - 8) * 128;
                out = Pt + (size_t)(cy - 8) * N_ITEM * 64; }
  const int tr = tid >> 4, tc = tid & 15;
  float acc[8][4] = {};
  for (int k0 = kc0; k0 < kc0 + Klen; k0 += 32) {
    __syncthreads();
#pragma unroll
    for (int lq = 0; lq < 4; ++lq) {           // A: 128 rows x 8 float4
      int u = tid + lq * 256;
      int r = u >> 3, kq = u & 7;
      int row = m0 + r; if (row > N_ITEM - 1) row = N_ITEM - 1;
      float4 a = *(const float4*)(X + (size_t)row * K + k0 + kq * 4);
      As[(kq * 4 + 0) * ASTR + r] = a.x;
      As[(kq * 4 + 1) * ASTR + r] = a.y;
      As[(kq * 4 + 2) * ASTR + r] = a.z;
      As[(kq * 4 + 3) * ASTR + r] = a.w;
    }
#pragma unroll
    for (int lq = 0; lq < 2; ++lq) {           // B: 32 rows x 16 float4
      int u = tid + lq * 256;
      int kb = u >> 4, nq = u & 15;
      *(float4*)(Bs + kb * 64 + nq * 4) =
          *(const float4*)(W + (size_t)(k0 + kb) * 64 + nq * 4);
    }
    __syncthreads();
#pragma unroll
    for (int k = 0; k < 32; ++k) {
      float4 a0 = *(const float4*)(As + k * ASTR + tr * 8);
      float4 a1 = *(const float4*)(As + k * ASTR + tr * 8 + 4);
      float4 b4 = *(const float4*)(Bs + k * 64 + tc * 4);
      float av[8] = {a0.x, a0.y, a0.z, a0.w, a1.x, a1.y, a1.z, a1.w};
      float bv[4] = {b4.x, b4.y, b4.z, b4.w};
#pragma unroll
      for (int ri = 0; ri < 8; ++ri)
#pragma unroll
        for (int ci = 0; ci < 4; ++ci) acc[ri][ci] += av[ri] * bv[ci];
    }
  }
#pragma unroll
  for (int ri = 0; ri < 8; ++ri) {
    int row = m0 + tr * 8 + ri;
    if (row < N_ITEM) {
      float4 o;
      o.x = acc[ri][0]; o.y = acc[ri][1]; o.z = acc[ri][2]; o.w = acc[ri][3];
      *(float4*)(out + (size_t)row * 64 + tc * 4) = o;
    }
  }
}

// ---------------- dual: sum partials + bias, L2-normalize, split bf16 --------
__global__ __launch_bounds__(256) void norm_dual(
    const float* __restrict__ Pi, const float* __restrict__ bi,
    unsigned short* __restrict__ Xhi, unsigned short* __restrict__ Xli,
    const float* __restrict__ Pt, const float* __restrict__ bt,
    unsigned short* __restrict__ Xht, unsigned short* __restrict__ Xlt)
{
  const float* P; const float* bias; unsigned short *Xh, *Xl; int nk;
  if (blockIdx.y == 0) { P = Pi; bias = bi; Xh = Xhi; Xl = Xli; nk = 8; }
  else                 { P = Pt; bias = bt; Xh = Xht; Xl = Xlt; nk = 3; }
  int row = blockIdx.x * 4 + (threadIdx.x >> 6);
  int lane = threadIdx.x & 63;
  size_t o = (size_t)row * 64 + lane;
  float v = bias[lane];
  for (int q = 0; q < nk; ++q) v += P[(size_t)q * N_ITEM * 64 + o];
  float ss = wred_sum(v * v);
  float xn = v * rsqrtf(ss);
  unsigned short hi = f2bf(xn);
  Xh[o] = hi;
  Xl[o] = f2bf(xn - bf2f(hi));
}

// ---------------- MFMA sim + branchless u32-key top-10, both modalities ------
// grid (63, NJC, 2), block 256 (4 waves, 128 i). Wave: 32 i (2x16 subtiles).
__global__ __launch_bounds__(256) void sim_topk_mfma(
    const unsigned short* __restrict__ Xhi, const unsigned short* __restrict__ Xli,
    const unsigned short* __restrict__ Xht, const unsigned short* __restrict__ Xlt,
    unsigned int* __restrict__ pk)
{
  __shared__ char lds[2 * 2 * 32 * 128];   // 16 KiB: [buf][hi/lo][32 rows][128B]
  const unsigned short* Xh = blockIdx.z ? Xht : Xhi;
  const unsigned short* Xl = blockIdx.z ? Xlt : Xli;
  unsigned int* pkm = pk + (size_t)blockIdx.z * N_ITEM * (NJC * 10);

  const int tid = threadIdx.x;
  const int l = tid & 63;
  const int wid = tid >> 6;
  const int ib = blockIdx.x * 128 + wid * 32;
  const int jc = blockIdx.y * JCH;
  const bool lastc = (jc + JCH > N_ITEM);   // wave-uniform (blockIdx.y == 15)

  // B-fragments (i side), loaded once. s = i-subtile, kh = K-half.
  bf16x8 bh[2][2], bl[2][2];
#pragma unroll
  for (int s = 0; s < 2; ++s) {
    int irow = ib + s * 16 + (l & 15);
    if (irow > N_ITEM - 1) irow = N_ITEM - 1;
    int ksl = (l >> 4) * 8;
#pragma unroll
    for (int kh = 0; kh < 2; ++kh) {
      bh[s][kh] = *(const bf16x8*)(Xh + (size_t)irow * 64 + kh * 32 + ksl);
      bl[s][kh] = *(const bf16x8*)(Xl + (size_t)irow * 64 + kh * 32 + ksl);
    }
  }

  unsigned int K0[10], K1[10];
#pragma unroll
  for (int t = 0; t < 10; ++t) { K0[t] = 0u; K1[t] = 0u; }

  auto stage = [&](int b, int p) {
    int row = tid >> 3, cb = (tid & 7) * 16;   // 256 16B-units per matrix
    int gr = jc + p * 32 + row;
    if (gr > N_ITEM - 1) gr = N_ITEM - 1;
    int4 vh = *(const int4*)(Xh + (size_t)gr * 64 + (cb >> 1));
    int4 vl = *(const int4*)(Xl + (size_t)gr * 64 + (cb >> 1));
    int bo = (row * 128 + cb) ^ ((row & 7) << 4);
    *(int4*)(lds + b * 8192 + bo) = vh;
    *(int4*)(lds + b * 8192 + 4096 + bo) = vl;
  };

// branchless epilogue: u32 keys through compare-exchange chains.
// MASKED only for the last chunk (jinv >= 192 <=> jj < 8000).
#define EPI(MASKED)                                                            \
  _Pragma("unroll")                                                            \
  for (int s = 0; s < 2; ++s) {                                                \
    unsigned int* K = s ? K1 : K0;                                             \
    _Pragma("unroll")                                                          \
    for (int t = 0; t < 2; ++t) {                                              \
      _Pragma("unroll")                                                        \
      for (int r = 0; r < 4; ++r) {                                            \
        float f = acc[t][s][r];                                                \
        unsigned int v19 = (unsigned int)(int)(f * 131072.0f + 131080.0f);     \
        unsigned int key = (v19 << 13) | (unsigned int)jinv[t * 4 + r];        \
        if (MASKED) key = (jinv[t * 4 + r] >= 192) ? key : 0u;                 \
        _Pragma("unroll")                                                      \
        for (int q = 0; q < 10; ++q) {                                         \
          unsigned int mn = umn(K[q], key);                                    \
          K[q] = umx(K[q], key);                                               \
          key = mn;                                                            \
        }                                                                      \
      }                                                                        \
    }                                                                          \
  }

  stage(0, 0);
  int cur = 0;
  for (int p = 0; p < 16; ++p) {           // 16 panels x 2 j-tiles
    __syncthreads();
    if (p < 15) stage(cur ^ 1, p + 1);
    const char* ldsH = lds + cur * 8192;
    const char* ldsL = ldsH + 4096;
    f32x4 acc[2][2] = {};
#pragma unroll
    for (int t = 0; t < 2; ++t) {
      int jr = t * 16 + (l & 15);
      int sw = (jr & 7) << 4;
      int rb = jr * 128 + ((l >> 4) << 4);
      bf16x8 ah0 = *(const bf16x8*)(ldsH + (rb ^ sw));
      bf16x8 ah1 = *(const bf16x8*)(ldsH + ((rb + 64) ^ sw));
      bf16x8 al0 = *(const bf16x8*)(ldsL + (rb ^ sw));
      bf16x8 al1 = *(const bf16x8*)(ldsL + ((rb + 64) ^ sw));
#pragma unroll
      for (int s = 0; s < 2; ++s) {
        acc[t][s] = __builtin_amdgcn_mfma_f32_16x16x32_bf16(ah0, bh[s][0], acc[t][s], 0, 0, 0);
        acc[t][s] = __builtin_amdgcn_mfma_f32_16x16x32_bf16(ah1, bh[s][1], acc[t][s], 0, 0, 0);
        acc[t][s] = __builtin_amdgcn_mfma_f32_16x16x32_bf16(ah0, bl[s][0], acc[t][s], 0, 0, 0);
        acc[t][s] = __builtin_amdgcn_mfma_f32_16x16x32_bf16(ah1, bl[s][1], acc[t][s], 0, 0, 0);
        acc[t][s] = __builtin_amdgcn_mfma_f32_16x16x32_bf16(al0, bh[s][0], acc[t][s], 0, 0, 0);
        acc[t][s] = __builtin_amdgcn_mfma_f32_16x16x32_bf16(al1, bh[s][1], acc[t][s], 0, 0, 0);
      }
    }
    const int jg0 = jc + p * 32 + ((l >> 4) << 2);
    int jinv[8];
#pragma unroll
    for (int t = 0; t < 2; ++t)
#pragma unroll
      for (int r = 0; r < 4; ++r)
        jinv[t * 4 + r] = 8191 - (jg0 + t * 16 + r);
    if (!lastc) { EPI(false) } else { EPI(true) }
    cur ^= 1;
  }
#undef EPI

  // in-wave merge of 4 lane-groups (shfl 16/32 tournament), lanes 0..15 store
#pragma unroll
  for (int s = 0; s < 2; ++s) {
    unsigned int* K = s ? K1 : K0;
    unsigned int kv[10];
#pragma unroll
    for (int t = 0; t < 10; ++t) {
      unsigned int m = K[0];
      m = umx(m, (unsigned int)__shfl_xor((int)m, 16, 64));
      m = umx(m, (unsigned int)__shfl_xor((int)m, 32, 64));
      bool own = (K[0] == m);
#pragma unroll
      for (int q2 = 0; q2 < 9; ++q2) K[q2] = own ? K[q2 + 1] : K[q2];
      K[9] = own ? 0u : K[9];
      kv[t] = m;
    }
    int i = ib + s * 16 + (l & 15);
    if (l < 16 && i < N_ITEM) {
      size_t base = ((size_t)i * NJC + blockIdx.y) * 10;
#pragma unroll
      for (int t = 0; t < 10; ++t) pkm[base + t] = kv[t];
    }
  }
}

// ---------------- merge 160 key candidates -> top-10 + dis (both mods) -------
__global__ __launch_bounds__(256) void merge_topk(
    const unsigned int* __restrict__ pk,
    float* __restrict__ tv_i, int* __restrict__ tc_i, float* __restrict__ dis_i,
    float* __restrict__ tv_t, int* __restrict__ tc_t, float* __restrict__ dis_t)
{
  float* tv; int* tc; float* dis;
  if (blockIdx.y == 0) { tv = tv_i; tc = tc_i; dis = dis_i; }
  else                 { tv = tv_t; tc = tc_t; dis = dis_t; }
  int lane = threadIdx.x & 63;
  int row = blockIdx.x * 4 + (threadIdx.x >> 6);
  size_t base = (size_t)blockIdx.y * N_ITEM * (NJC * 10) + (size_t)row * (NJC * 10);
  unsigned int k0 = pk[base + lane];
  unsigned int k1 = pk[base + 64 + lane];
  unsigned int k2 = (lane < 32) ? pk[base + 128 + lane] : 0u;
  float deg = 0.f, keepv = 0.f; int keepc = 0;
  for (int t = 0; t < 10; ++t) {
    unsigned int m = umx(umx(k0, k1), k2);
#pragma unroll
    for (int off = 32; off; off >>= 1)
      m = umx(m, (unsigned int)__shfl_xor((int)m, off, 64));
    deg += key_val(m);
    if (k0 == m) k0 = 0u;
    else if (k1 == m) k1 = 0u;
    else if (k2 == m) k2 = 0u;
    if (lane == t) { keepv = key_val(m); keepc = key_idx(m); }
  }
  if (lane < 10) { tv[(size_t)row * 10 + lane] = keepv; tc[(size_t)row * 10 + lane] = keepc; }
  if (lane == 0) dis[row] = deg > 0.f ? rsqrtf(deg) : 0.f;
}

// ---------------- fused SPMM (both modalities) + attention + h_norm ----------
__global__ __launch_bounds__(256) void spmm_attn(
    const float* __restrict__ tv_i, const int* __restrict__ tc_i, const float* __restrict__ dis_i,
    const float* __restrict__ ow_i, const int* __restrict__ oc_i,
    const float* __restrict__ tv_t, const int* __restrict__ tc_t, const float* __restrict__ dis_t,
    const float* __restrict__ ow_t, const int* __restrict__ oc_t,
    const float* __restrict__ item_emb,
    const float* __restrict__ Wq1, const float* __restrict__ bq1,
    const float* __restrict__ wq2, float* __restrict__ hn)
{
  __shared__ float Wlds[64 * 64];
  __shared__ float sm[4][2][64];
  int tid = threadIdx.x;
  int lane = tid & 63, wid = tid >> 6;
  int row = blockIdx.x * 4 + wid;
#pragma unroll
  for (int s = 0; s < 4; ++s) {
    int idx = tid + s * 256;
    ((float4*)Wlds)[idx] = ((const float4*)Wq1)[idx];
  }
  float a0 = 0.f, a1 = 0.f;
  {
    float disr = dis_i[row];
#pragma unroll
    for (int t = 0; t < 10; ++t) {
      int c = tc_i[(size_t)row * 10 + t];
      a0 += 0.1f * disr * tv_i[(size_t)row * 10 + t] * dis_i[c] * item_emb[(size_t)c * 64 + lane];
    }
#pragma unroll
    for (int t = 0; t < 10; ++t) {
      int c = oc_i[(size_t)row * 10 + t];
      a0 += 0.9f * ow_i[(size_t)row * 10 + t] * item_emb[(size_t)c * 64 + lane];
    }
  }
  {
    float disr = dis_t[row];
#pragma unroll
    for (int t = 0; t < 10; ++t) {
      int c = tc_t[(size_t)row * 10 + t];
      a1 += 0.1f * disr * tv_t[(size_t)row * 10 + t] * dis_t[c] * item_emb[(size_t)c * 64 + lane];
    }
#pragma unroll
    for (int t = 0; t < 10; ++t) {
      int c = oc_t[(size_t)row * 10 + t];
      a1 += 0.9f * ow_t[(size_t)row * 10 + t] * item_emb[(size_t)c * 64 + lane];
    }
  }
  sm[wid][0][lane] = a0;
  sm[wid][1][lane] = a1;
  __syncthreads();
  float y0 = bq1[lane], y1 = bq1[lane];
  for (int k = 0; k < 64; ++k) {
    float w = Wlds[k * 64 + lane];
    y0 += sm[wid][0][k] * w;
    y1 += sm[wid][1][k] * w;
  }
  float wq = wq2[lane];
  float s0 = wred_sum(tanhf(y0) * wq);
  float s1 = wred_sum(tanhf(y1) * wq);
  float mx = fmaxf(s0, s1);
  float e0 = expf(s0 - mx), e1 = expf(s1 - mx);
  float inv = 1.f / (e0 + e1);
  float h = (e0 * inv) * a0 + (e1 * inv) * a1;
  float n2 = wred_sum(h * h);
  float nrm = fmaxf(sqrtf(n2), 1e-12f);
  hn[(size_t)row * 64 + lane] = h / nrm;
}

// ---------------- UI graph helpers -------------------------------------------
__global__ void ui_zero(int* degi, int* cursor)
{
  int n = blockIdx.x * 256 + threadIdx.x;
  if (n < N_NODE) { degi[n] = 0; cursor[n] = 0; }
}

__global__ void ui_count(const int* __restrict__ r, int* degi)
{
  int e = blockIdx.x * 256 + threadIdx.x;
  if (e < N_EDGE) atomicAdd(&degi[r[e]], 1);
}

// coalesced 3-kernel scan
__global__ __launch_bounds__(256) void ui_blocksum(const int* __restrict__ degi, int* __restrict__ bsum)
{
  __shared__ int ws4[4];
  int tid = threadIdx.x;
  int v = degi[blockIdx.x * 256 + tid];
#pragma unroll
  for (int off = 32; off; off >>= 1) v += __shfl_xor(v, off, 64);
  if ((tid & 63) == 0) ws4[tid >> 6] = v;
  __syncthreads();
  if (tid == 0) bsum[blockIdx.x] = ws4[0] + ws4[1] + ws4[2] + ws4[3];
}

__global__ __launch_bounds__(128) void ui_scanb(const int* __restrict__ bsum, int* __restrict__ bbase, int* __restrict__ offs)
{
  __shared__ int s[128];
  int t = threadIdx.x;
  int v = (t < 125) ? bsum[t] : 0;
  s[t] = v;
  __syncthreads();
  for (int off = 1; off < 128; off <<= 1) {
    int tmp = (t >= off) ? s[t - off] : 0;
    __syncthreads();
    s[t] += tmp;
    __syncthreads();
  }
  if (t < 125) bbase[t] = s[t] - v;
  if (t == 127) offs[N_NODE] = s[127];
}

__global__ __launch_bounds__(256) void ui_scanc(const int* __restrict__ degi, const int* __restrict__ bbase,
                                                int* __restrict__ offs, float* __restrict__ disui)
{
  __shared__ int wt[4];
  int tid = threadIdx.x;
  int i = blockIdx.x * 256 + tid;
  int d = degi[i];
  int v = d;
#pragma unroll
  for (int off = 1; off < 64; off <<= 1) {
    int n = __shfl_up(v, off, 64);
    if ((tid & 63) >= off) v += n;
  }
  if ((tid & 63) == 63) wt[tid >> 6] = v;
  __syncthreads();
  int add = bbase[blockIdx.x];
  for (int w = 0; w < (tid >> 6); ++w) add += wt[w];
  offs[i] = add + v - d;
  disui[i] = d > 0 ? rsqrtf((float)d) : 0.f;
}

__global__ void ui_fill(const int* __restrict__ r, const int* __restrict__ c,
                        const int* __restrict__ offs, int* cursor, int* __restrict__ csr)
{
  int e = blockIdx.x * 256 + threadIdx.x;
  if (e < N_EDGE) {
    int rr = r[e];
    int pos = offs[rr] + atomicAdd(&cursor[rr], 1);
    csr[pos] = c[e];
  }
}

// wave per row; 8 edges in flight (8 lanes x 8 floats each); FINAL fuses mean+h
template <bool FIRST, bool FINAL>
__global__ __launch_bounds__(256) void ui_prop(
    const float* __restrict__ in, const float* __restrict__ ue,
    const float* __restrict__ ie, float* __restrict__ out,
    const int* __restrict__ offs, const int* __restrict__ csr,
    const float* __restrict__ dis, const float* __restrict__ hn)
{
  int tid = threadIdx.x;
  int lane = tid & 63, wid = tid >> 6;
  int row = blockIdx.x * 4 + wid;
  int q = lane >> 3, c8 = lane & 7;        // q: edge slot, c8: 8 floats each
  float4 acc0 = make_float4(0.f, 0.f, 0.f, 0.f);
  float4 acc1 = make_float4(0.f, 0.f, 0.f, 0.f);
  int e0 = offs[row], e1 = offs[row + 1];
  for (int e = e0 + q; e < e1; e += 8) {
    int cc = csr[e];
    const float* src = FIRST
        ? (cc < N_USER ? ue + (size_t)cc * 64 : ie + (size_t)(cc - N_USER) * 64)
        : in + (size_t)cc * 64;
    float4 v0 = *(const float4*)(src + c8 * 8);
    float4 v1 = *(const float4*)(src + c8 * 8 + 4);
    float d = dis[cc];
    acc0.x += d * v0.x; acc0.y += d * v0.y; acc0.z += d * v0.z; acc0.w += d * v0.w;
    acc1.x += d * v1.x; acc1.y += d * v1.y; acc1.z += d * v1.z; acc1.w += d * v1.w;
  }
#pragma unroll
  for (int off = 8; off <= 32; off <<= 1) {
    acc0.x += __shfl_xor(acc0.x, off, 64);
    acc0.y += __shfl_xor(acc0.y, off, 64);
    acc0.z += __shfl_xor(acc0.z, off, 64);
    acc0.w += __shfl_xor(acc0.w, off, 64);
    acc1.x += __shfl_xor(acc1.x, off, 64);
    acc1.y += __shfl_xor(acc1.y, off, 64);
    acc1.z += __shfl_xor(acc1.z, off, 64);
    acc1.w += __shfl_xor(acc1.w, off, 64);
  }
  if (q == 0) {
    float dr = dis[row];
    acc0.x *= dr; acc0.y *= dr; acc0.z *= dr; acc0.w *= dr;
    acc1.x *= dr; acc1.y *= dr; acc1.z *= dr; acc1.w *= dr;
    if (!FINAL) {
      *(float4*)(out + (size_t)row * 64 + c8 * 8) = acc0;
      *(float4*)(out + (size_t)row * 64 + c8 * 8 + 4) = acc1;
    } else {
      const float* egop = (row < N_USER) ? ue + (size_t)row * 64
                                         : ie + (size_t)(row - N_USER) * 64;
      float4 eg0 = *(const float4*)(egop + c8 * 8);
      float4 eg1 = *(const float4*)(egop + c8 * 8 + 4);
      float4 l10 = *(const float4*)(in + (size_t)row * 64 + c8 * 8);
      float4 l11 = *(const float4*)(in + (size_t)row * 64 + c8 * 8 + 4);
      float4 o0, o1;
      o0.x = (eg0.x + l10.x + acc0.x) * (1.f / 3.f);
      o0.y = (eg0.y + l10.y + acc0.y) * (1.f / 3.f);
      o0.z = (eg0.z + l10.z + acc0.z) * (1.f / 3.f);
      o0.w = (eg0.w + l10.w + acc0.w) * (1.f / 3.f);
      o1.x = (eg1.x + l11.x + acc1.x) * (1.f / 3.f);
      o1.y = (eg1.y + l11.y + acc1.y) * (1.f / 3.f);
      o1.z = (eg1.z + l11.z + acc1.z) * (1.f / 3.f);
      o1.w = (eg1.w + l11.w + acc1.w) * (1.f / 3.f);
      if (row >= N_USER) {
        const float* hp = hn + (size_t)(row - N_USER) * 64;
        float4 h0 = *(const float4*)(hp + c8 * 8);
        float4 h1 = *(const float4*)(hp + c8 * 8 + 4);
        o0.x += h0.x; o0.y += h0.y; o0.z += h0.z; o0.w += h0.w;
        o1.x += h1.x; o1.y += h1.y; o1.z += h1.z; o1.w += h1.w;
      }
      *(float4*)(out + (size_t)row * 64 + c8 * 8) = o0;
      *(float4*)(out + (size_t)row * 64 + c8 * 8 + 4) = o1;
    }
  }
}

// ---------------- host driver ------------------------------------------------
extern "C" void kernel_launch(void* const* d_in, const int* in_sizes, int n_in,
                              void* d_out, int out_size, void* d_ws, size_t ws_size,
                              hipStream_t stream)
{
  (void)in_sizes; (void)n_in; (void)out_size; (void)ws_size;
  const float* user_emb = (const float*)d_in[0];
  const float* item_emb = (const float*)d_in[1];
  const float* v_feat   = (const float*)d_in[2];
  const float* t_feat   = (const float*)d_in[3];
  const float* W_v      = (const float*)d_in[4];
  const float* b_v      = (const float*)d_in[5];
  const float* W_t      = (const float*)d_in[6];
  const float* b_t      = (const float*)d_in[7];
  const float* Wq1      = (const float*)d_in[8];
  const float* bq1      = (const float*)d_in[9];
  const float* wq2      = (const float*)d_in[10];
  const float* ow_i     = (const float*)d_in[11];
  const float* ow_t     = (const float*)d_in[12];
  const int*   eidx     = (const int*)d_in[13];
  const int*   oc_i     = (const int*)d_in[14];
  const int*   oc_t     = (const int*)d_in[15];
  float* out = (float*)d_out;

  char* wp = (char*)d_ws;
  auto alloc = [&](size_t bytes) -> void* {
    void* p = (void*)wp;
    wp += (bytes + 255) & ~(size_t)255;
    return p;
  };
  // region A: Pp_i (8 x 2.05 MB) -> later pk (2 x 5.12 MB)
  char* regionA = (char*)alloc((size_t)8 * N_ITEM * 64 * 4 + 1024);
  // region B: Pp_t (3 x 2.05 MB) -> later E1 (8.19 MB)
  char* regionB = (char*)alloc((size_t)N_NODE * 64 * 4 + 1024);
  float* Pp_i = (float*)regionA;
  float* Pp_t = (float*)regionB;
  unsigned int* pk = (unsigned int*)regionA;    // alive after norm_dual
  float* E1 = (float*)regionB;                  // alive after merge/spmm

  unsigned short* Xhi = (unsigned short*)alloc((size_t)N_ITEM * 64 * 2);
  unsigned short* Xli = (unsigned short*)alloc((size_t)N_ITEM * 64 * 2);
  unsigned short* Xht = (unsigned short*)alloc((size_t)N_ITEM * 64 * 2);
  unsigned short* Xlt = (unsigned short*)alloc((size_t)N_ITEM * 64 * 2);
  float* tv_i  = (float*)alloc((size_t)N_ITEM * 10 * 4);
  int*   tc_i  = (int*)  alloc((size_t)N_ITEM * 10 * 4);
  float* dis_i = (float*)alloc((size_t)N_ITEM * 4);
  float* tv_t  = (float*)alloc((size_t)N_ITEM * 10 * 4);
  int*   tc_t  = (int*)  alloc((size_t)N_ITEM * 10 * 4);
  float* dis_t = (float*)alloc((size_t)N_ITEM * 4);
  float* hn    = (float*)alloc((size_t)N_ITEM * 64 * 4);
  int*   degi  = (int*)  alloc((size_t)N_NODE * 4);
  int*   curs  = (int*)  alloc((size_t)N_NODE * 4);
  int*   offs  = (int*)  alloc((size_t)(N_NODE + 1) * 4);
  float* disui = (float*)alloc((size_t)N_NODE * 4);
  int*   csr   = (int*)  alloc((size_t)N_EDGE * 4);
  int*   bsum  = (int*)  alloc((size_t)128 * 4);
  int*   bbase = (int*)  alloc((size_t)128 * 4);

  // ---- projections (both modalities, one launch) ----
  gemm_dual<<<dim3(63, 11), 256, 0, stream>>>(v_feat, W_v, t_feat, W_t, Pp_i, Pp_t);
  norm_dual<<<dim3(2000, 2), 256, 0, stream>>>(Pp_i, b_v, Xhi, Xli, Pp_t, b_t, Xht, Xlt);
  // ---- sim + topk (both modalities, one launch) ----
  sim_topk_mfma<<<dim3(63, NJC, 2), 256, 0, stream>>>(Xhi, Xli, Xht, Xlt, pk);
  merge_topk<<<dim3(2000, 2), 256, 0, stream>>>(pk, tv_i, tc_i, dis_i, tv_t, tc_t, dis_t);
  // ---- fused SPMM + attention + h_norm ----
  spmm_attn<<<2000, 256, 0, stream>>>(tv_i, tc_i, dis_i, ow_i, oc_i,
                                      tv_t, tc_t, dis_t, ow_t, oc_t,
                                      item_emb, Wq1, bq1, wq2, hn);
  // ---- user-item graph ----
  ui_zero<<<125, 256, 0, stream>>>(degi, curs);
  ui_count<<<N_EDGE / 256, 256, 0, stream>>>(eidx, degi);
  ui_blocksum<<<125, 256, 0, stream>>>(degi, bsum);
  ui_scanb<<<1, 128, 0, stream>>>(bsum, bbase, offs);
  ui_scanc<<<125, 256, 0, stream>>>(degi, bbase, offs, disui);
  ui_fill<<<N_EDGE / 256, 256, 0, stream>>>(eidx, eidx + N_EDGE, offs, curs, csr);
  ui_prop<true, false><<<8000, 256, 0, stream>>>(nullptr, user_emb, item_emb, E1, offs, csr, disui, nullptr);
  ui_prop<false, true><<<8000, 256, 0, stream>>>(E1, user_emb, item_emb, out, offs, csr, disui, hn);
}